// Round 4
// baseline (6982.902 us; speedup 1.0000x reference)
//
#include <hip/hip_runtime.h>
#include <math.h>

#define Nn 50000
#define Ee 1600000
#define Gg 64

// ---------------- one-time CSR build ----------------
__global__ void k_hist(const int* __restrict__ ei, int* __restrict__ deg) {
    int e = blockIdx.x * blockDim.x + threadIdx.x;
    if (e < Ee) atomicAdd(&deg[ei[Ee + e]], 1);
}

__global__ void k_scan1(const int* __restrict__ deg, int* __restrict__ row_ptr,
                        int* __restrict__ bsum) {
    __shared__ int buf[256];
    int i = blockIdx.x * 256 + threadIdx.x;
    int v = (i < Nn) ? deg[i] : 0;
    buf[threadIdx.x] = v;
    __syncthreads();
    for (int off = 1; off < 256; off <<= 1) {
        int t = (threadIdx.x >= off) ? buf[threadIdx.x - off] : 0;
        __syncthreads();
        buf[threadIdx.x] += t;
        __syncthreads();
    }
    if (i < Nn) row_ptr[i + 1] = buf[threadIdx.x];  // block-local inclusive
    if (threadIdx.x == 255) bsum[blockIdx.x] = buf[255];
}

__global__ void k_scan2(int* __restrict__ bsum, int nb) {
    __shared__ int buf[256];
    int v = (threadIdx.x < nb) ? bsum[threadIdx.x] : 0;
    buf[threadIdx.x] = v;
    __syncthreads();
    for (int off = 1; off < 256; off <<= 1) {
        int t = (threadIdx.x >= off) ? buf[threadIdx.x - off] : 0;
        __syncthreads();
        buf[threadIdx.x] += t;
        __syncthreads();
    }
    if (threadIdx.x < nb) bsum[threadIdx.x] = buf[threadIdx.x];  // inclusive
}

__global__ void k_scan3(int* __restrict__ row_ptr, const int* __restrict__ bsum) {
    int i = blockIdx.x * 256 + threadIdx.x;  // i in [0, Nn]
    if (i > Nn) return;
    if (i == 0) { row_ptr[0] = 0; return; }
    int b = (i - 1) >> 8;
    if (b > 0) row_ptr[i] += bsum[b - 1];
}

__global__ void k_scatter(const int* __restrict__ ei, int* __restrict__ cursor,
                          int* __restrict__ src_perm, int* __restrict__ eperm,
                          int* __restrict__ dst_sorted) {
    int e = blockIdx.x * blockDim.x + threadIdx.x;
    if (e >= Ee) return;
    int dst = ei[Ee + e];
    int pos = atomicAdd(&cursor[dst], 1);
    src_perm[pos] = ei[e];
    eperm[pos] = e;
    dst_sorted[pos] = dst;
}

__global__ void k_gbound(const int* __restrict__ batch, int* __restrict__ gstart) {
    int n = blockIdx.x * blockDim.x + threadIdx.x;
    if (n >= Nn) return;
    int b = batch[n];
    if (n == 0) { for (int g = 0; g <= b; ++g) gstart[g] = 0; }
    else { int bp = batch[n - 1]; for (int g = bp + 1; g <= b; ++g) gstart[g] = n; }
    if (n == Nn - 1) { for (int g = b + 1; g <= Gg; ++g) gstart[g] = Nn; }
}

// ---------------- node kernels ----------------
// h = relu(x @ Wn + bn). Register-blocked: x-tile in LDS, Wn chunk in regs.
__global__ void k_encode(const float* __restrict__ x, const float* __restrict__ Wn,
                         const float* __restrict__ bn, float* __restrict__ h) {
    __shared__ float sx[64 * 32];
    int base = blockIdx.x * 64;
    for (int i = threadIdx.x; i < 512; i += 256) {        // 64 rows x 32 cols, float4
        int off = i * 4, row = off >> 5;
        float4 v = (base + row < Nn) ? ((const float4*)(x))[(base * 32 + off) >> 2]
                                     : make_float4(0.f, 0.f, 0.f, 0.f);
        ((float4*)sx)[i] = v;
    }
    __syncthreads();
    int lane = threadIdx.x & 63, wv = threadIdx.x >> 6;
    float acc[16];
    float b = bn[lane];
#pragma unroll
    for (int nn = 0; nn < 16; ++nn) acc[nn] = b;
#pragma unroll
    for (int k0 = 0; k0 < 32; k0 += 4) {
        float w0 = Wn[(k0 + 0) * 64 + lane];
        float w1 = Wn[(k0 + 1) * 64 + lane];
        float w2 = Wn[(k0 + 2) * 64 + lane];
        float w3 = Wn[(k0 + 3) * 64 + lane];
#pragma unroll
        for (int nn = 0; nn < 16; ++nn) {
            int row = wv * 16 + nn;
            float4 hv = *(const float4*)&sx[row * 32 + k0];
            acc[nn] = fmaf(hv.x, w0, fmaf(hv.y, w1, fmaf(hv.z, w2, fmaf(hv.w, w3, acc[nn]))));
        }
    }
#pragma unroll
    for (int nn = 0; nn < 16; ++nn) {
        int n = base + wv * 16 + nn;
        if (n < Nn) h[(size_t)n * 64 + lane] = fmaxf(acc[nn], 0.f);
    }
}

// Wqm[j][l'=(h,i)] = sum_c Wq[j][h*16+c] * We[i][h*16+c];  bqm likewise from bq
__global__ void k_wqm(const float* __restrict__ Wq, const float* __restrict__ bq,
                      const float* __restrict__ We, float* __restrict__ Wqm,
                      float* __restrict__ bqm) {
    for (int o = threadIdx.x; o < 64 * 64; o += 256) {
        int j = o >> 6, lp = o & 63, hh = lp >> 4, ii = lp & 15;
        float acc = 0.f;
#pragma unroll
        for (int c = 0; c < 16; ++c)
            acc += Wq[j * 64 + hh * 16 + c] * We[ii * 64 + hh * 16 + c];
        Wqm[o] = acc;
    }
    if (threadIdx.x < 64) {
        int hh = threadIdx.x >> 4, ii = threadIdx.x & 15;
        float acc = 0.f;
#pragma unroll
        for (int c = 0; c < 16; ++c)
            acc += bq[hh * 16 + c] * We[ii * 64 + hh * 16 + c];
        bqm[threadIdx.x] = acc;
    }
}

// qn,kn,vn,tq,sn = h@{Wq,Wk,Wv,Wqm,Ws}+bias. Register-blocked 5-in-1 GEMM:
// h-tile (64x64) in LDS, weight k-chunk (4x5) in regs, acc[5][16] unrolled.
__global__ void k_qkvt(const float* __restrict__ h,
                       const float* __restrict__ Wq, const float* __restrict__ bq,
                       const float* __restrict__ Wk, const float* __restrict__ bk,
                       const float* __restrict__ Wv, const float* __restrict__ bv,
                       const float* __restrict__ Wqm, const float* __restrict__ bqm,
                       const float* __restrict__ Ws, const float* __restrict__ bs,
                       float* __restrict__ qn, float* __restrict__ kn,
                       float* __restrict__ vn, float* __restrict__ tq,
                       float* __restrict__ sn) {
    __shared__ float sh[64 * 64];
    int base = blockIdx.x * 64;
    for (int i = threadIdx.x; i < 1024; i += 256) {       // 64 rows x 64 cols, float4
        int off = i * 4, row = off >> 6;
        float4 v = (base + row < Nn) ? ((const float4*)(h))[((size_t)base * 64 + off) >> 2]
                                     : make_float4(0.f, 0.f, 0.f, 0.f);
        ((float4*)sh)[i] = v;
    }
    __syncthreads();
    int lane = threadIdx.x & 63, wv = threadIdx.x >> 6;
    float aq[16], ak[16], av[16], at[16], as_[16];
    float _bq = bq[lane], _bk = bk[lane], _bv = bv[lane], _bt = bqm[lane], _bs = bs[lane];
#pragma unroll
    for (int nn = 0; nn < 16; ++nn) {
        aq[nn] = _bq; ak[nn] = _bk; av[nn] = _bv; at[nn] = _bt; as_[nn] = _bs;
    }
#pragma unroll
    for (int k0 = 0; k0 < 64; k0 += 4) {
        float wq[4], wk[4], wvv[4], wt[4], ws[4];
#pragma unroll
        for (int j = 0; j < 4; ++j) {
            wq[j] = Wq[(k0 + j) * 64 + lane];
            wk[j] = Wk[(k0 + j) * 64 + lane];
            wvv[j] = Wv[(k0 + j) * 64 + lane];
            wt[j] = Wqm[(k0 + j) * 64 + lane];
            ws[j] = Ws[(k0 + j) * 64 + lane];
        }
#pragma unroll
        for (int nn = 0; nn < 16; ++nn) {
            int row = wv * 16 + nn;
            float4 hv = *(const float4*)&sh[row * 64 + k0];
            aq[nn] = fmaf(hv.x, wq[0], fmaf(hv.y, wq[1], fmaf(hv.z, wq[2], fmaf(hv.w, wq[3], aq[nn]))));
            ak[nn] = fmaf(hv.x, wk[0], fmaf(hv.y, wk[1], fmaf(hv.z, wk[2], fmaf(hv.w, wk[3], ak[nn]))));
            av[nn] = fmaf(hv.x, wvv[0], fmaf(hv.y, wvv[1], fmaf(hv.z, wvv[2], fmaf(hv.w, wvv[3], av[nn]))));
            at[nn] = fmaf(hv.x, wt[0], fmaf(hv.y, wt[1], fmaf(hv.z, wt[2], fmaf(hv.w, wt[3], at[nn]))));
            as_[nn] = fmaf(hv.x, ws[0], fmaf(hv.y, ws[1], fmaf(hv.z, ws[2], fmaf(hv.w, ws[3], as_[nn]))));
        }
    }
#pragma unroll
    for (int nn = 0; nn < 16; ++nn) {
        int n = base + wv * 16 + nn;
        if (n < Nn) {
            size_t o = (size_t)n * 64 + lane;
            qn[o] = aq[nn]; kn[o] = ak[nn]; vn[o] = av[nn]; tq[o] = at[nn]; sn[o] = as_[nn];
        }
    }
}

// edge-parallel, CSR order: alpha[idx][h] = 0.25*(q[d]·k[s] + ea[e]·tq[d])
__global__ void k_alpha(const float* __restrict__ qn, const float* __restrict__ kn,
                        const float* __restrict__ tq, const int* __restrict__ src_perm,
                        const int* __restrict__ dst_sorted, const int* __restrict__ eperm,
                        const float* __restrict__ ea, float* __restrict__ alpha) {
    __shared__ float ea_s[64 * 16];
    __shared__ float al_s[64 * 4];
    int base = blockIdx.x * 64;
    {   // stage 64 edges' ea rows (float4-coalesced gather)
        int t = threadIdx.x;
        int idx = base + (t >> 2);
        if (idx < Ee) {
            int e = eperm[idx];
            ((float4*)ea_s)[t] = ((const float4*)(ea + (size_t)e * 16))[t & 3];
        }
    }
    __syncthreads();
    int lane = threadIdx.x & 63, wv = threadIdx.x >> 6;
    int hh = lane >> 4, cc = lane & 15;
    for (int it = 0; it < 16; ++it) {
        int el = wv * 16 + it;
        int idx = base + el;
        if (idx < Ee) {
            int s = src_perm[idx], d = dst_sorted[idx];
            float q = qn[(size_t)d * 64 + lane];
            float k = kn[(size_t)s * 64 + lane];
            float t = tq[(size_t)d * 64 + lane];
            float part = q * k + ea_s[el * 16 + cc] * t;
            part += __shfl_xor(part, 1, 16);
            part += __shfl_xor(part, 2, 16);
            part += __shfl_xor(part, 4, 16);
            part += __shfl_xor(part, 8, 16);
            if (cc == 0) al_s[el * 4 + hh] = part * 0.25f;
        }
    }
    __syncthreads();
    {
        long gi = (long)base * 4 + threadIdx.x;
        if (gi < (long)Ee * 4) alpha[gi] = al_s[threadIdx.x];
    }
}

// node-parallel aggregation: max sweep + 4-way-unrolled weighted sums, then
// (acce)@We transform + skip + relu + residual. No atomics.
__global__ void k_agg(float* __restrict__ h, const float* __restrict__ vn,
                      const float* __restrict__ sn, const float* __restrict__ alpha,
                      const int* __restrict__ row_ptr, const int* __restrict__ src_perm,
                      const int* __restrict__ eperm, const float* __restrict__ ea,
                      const float* __restrict__ We) {
    __shared__ float sWe[1024];
    __shared__ float tile[4][64];
    for (int t = threadIdx.x; t < 1024; t += 256) sWe[t] = We[t];
    __syncthreads();
    int lane = threadIdx.x & 63, wv = threadIdx.x >> 6;
    int hh = lane >> 4, cc = lane & 15;
    int n = blockIdx.x * 4 + wv;
    if (n >= Nn) return;
    int beg = row_ptr[n], end = row_ptr[n + 1];
    // sweep 1: per-head max (coalesced: 64 lanes cover 16 edges x 4 heads)
    float vm = -INFINITY;
    for (int b = beg; b < end; b += 16) {
        int j = b + cc;
        if (j < end) vm = fmaxf(vm, alpha[(size_t)j * 4 + hh]);
    }
    vm = fmaxf(vm, __shfl_xor(vm, 1, 16));
    vm = fmaxf(vm, __shfl_xor(vm, 2, 16));
    vm = fmaxf(vm, __shfl_xor(vm, 4, 16));
    vm = fmaxf(vm, __shfl_xor(vm, 8, 16));
    // sweep 2: weighted accumulation, 4 edges in flight
    float accv = 0.f, acce = 0.f, accd = 0.f;
    int idx = beg;
    for (; idx + 4 <= end; idx += 4) {
        int s0 = src_perm[idx], s1 = src_perm[idx + 1], s2 = src_perm[idx + 2], s3 = src_perm[idx + 3];
        int e0 = eperm[idx], e1 = eperm[idx + 1], e2 = eperm[idx + 2], e3 = eperm[idx + 3];
        float a0 = alpha[(size_t)idx * 4 + hh], a1 = alpha[(size_t)(idx + 1) * 4 + hh];
        float a2 = alpha[(size_t)(idx + 2) * 4 + hh], a3 = alpha[(size_t)(idx + 3) * 4 + hh];
        float v0 = vn[(size_t)s0 * 64 + lane], v1 = vn[(size_t)s1 * 64 + lane];
        float v2 = vn[(size_t)s2 * 64 + lane], v3 = vn[(size_t)s3 * 64 + lane];
        float x0 = ea[(size_t)e0 * 16 + cc], x1 = ea[(size_t)e1 * 16 + cc];
        float x2 = ea[(size_t)e2 * 16 + cc], x3 = ea[(size_t)e3 * 16 + cc];
        float p0 = __expf(a0 - vm), p1 = __expf(a1 - vm);
        float p2 = __expf(a2 - vm), p3 = __expf(a3 - vm);
        accd += (p0 + p1) + (p2 + p3);
        accv = fmaf(p0, v0, fmaf(p1, v1, fmaf(p2, v2, fmaf(p3, v3, accv))));
        acce = fmaf(p0, x0, fmaf(p1, x1, fmaf(p2, x2, fmaf(p3, x3, acce))));
    }
    for (; idx < end; ++idx) {
        int s0 = src_perm[idx], e0 = eperm[idx];
        float p0 = __expf(alpha[(size_t)idx * 4 + hh] - vm);
        accd += p0;
        accv = fmaf(p0, vn[(size_t)s0 * 64 + lane], accv);
        acce = fmaf(p0, ea[(size_t)e0 * 16 + cc], acce);
    }
    float inv = 1.f / (accd + 1e-16f);
    tile[wv][lane] = acce * inv;  // (h,i) layout, wave-local LDS (no barrier needed)
    float re = 0.f;
#pragma unroll
    for (int i = 0; i < 16; ++i)
        re = fmaf(tile[wv][hh * 16 + i], sWe[i * 64 + lane], re);
    size_t o = (size_t)n * 64 + lane;
    float hv = h[o];
    h[o] = hv + fmaxf(accv * inv + re + sn[o], 0.f);
}

// mean-pool per group (batch sorted -> boundaries) + fused MLP head
__global__ void k_pool(const float* __restrict__ h, const int* __restrict__ gstart,
                       const float* __restrict__ W1, const float* __restrict__ b1,
                       const float* __restrict__ W2, const float* __restrict__ b2,
                       float* __restrict__ out) {
    int g = blockIdx.x;
    int lane = threadIdx.x & 63, wv = threadIdx.x >> 6;
    int beg = gstart[g], end = gstart[g + 1];
    __shared__ float red[4][64];
    __shared__ float sp[64];
    __shared__ float sh[32];
    float acc = 0.f;
    for (int n = beg + wv; n < end; n += 4) acc += h[(size_t)n * 64 + lane];
    red[wv][lane] = acc;
    __syncthreads();
    if (threadIdx.x < 64) {
        float c = fmaxf((float)(end - beg), 1.f);
        sp[lane] = (red[0][lane] + red[1][lane] + red[2][lane] + red[3][lane]) / c;
    }
    __syncthreads();
    if (threadIdx.x < 32) {
        int t = threadIdx.x;
        float a = b1[t];
#pragma unroll
        for (int i = 0; i < 64; ++i) a = fmaf(sp[i], W1[i * 32 + t], a);
        sh[t] = fmaxf(a, 0.f) * W2[t];
    }
    __syncthreads();
    if (threadIdx.x == 0) {
        float s = b2[0];
#pragma unroll
        for (int i = 0; i < 32; ++i) s += sh[i];
        out[g] = s;
    }
}

extern "C" void kernel_launch(void* const* d_in, const int* in_sizes, int n_in,
                              void* d_out, int out_size, void* d_ws, size_t ws_size,
                              hipStream_t stream) {
    const float* x   = (const float*)d_in[0];
    const int*   ei  = (const int*)d_in[1];
    const float* ea  = (const float*)d_in[2];
    const int*   bat = (const int*)d_in[3];
    const float* Wn  = (const float*)d_in[4];
    const float* bn  = (const float*)d_in[5];
    const float* Wq  = (const float*)d_in[6];
    const float* bq  = (const float*)d_in[7];
    const float* Wk  = (const float*)d_in[8];
    const float* bk  = (const float*)d_in[9];
    const float* Wv  = (const float*)d_in[10];
    const float* bv  = (const float*)d_in[11];
    const float* We  = (const float*)d_in[12];
    const float* Wsk = (const float*)d_in[13];
    const float* bs  = (const float*)d_in[14];
    const float* W1  = (const float*)d_in[15];
    const float* b1  = (const float*)d_in[16];
    const float* W2  = (const float*)d_in[17];
    const float* b2  = (const float*)d_in[18];
    float* out = (float*)d_out;

    const size_t NH = (size_t)Nn * 64;
    float* h    = (float*)d_ws;
    float* qn   = h + NH;
    float* kn   = h + 2 * NH;
    float* vn   = h + 3 * NH;
    float* tq   = h + 4 * NH;
    float* sn   = h + 5 * NH;
    float* alpha = h + 6 * NH;                 // E*4
    float* Wqm  = alpha + (size_t)Ee * 4;      // 4096
    float* bqm  = Wqm + 4096;                  // 64
    int* deg       = (int*)(bqm + 64);         // N
    int* row_ptr   = deg + Nn;                 // N+1
    int* cursor    = row_ptr + Nn + 1;         // N
    int* src_perm  = cursor + Nn;              // E
    int* eperm     = src_perm + Ee;            // E
    int* dst_sorted = eperm + Ee;              // E
    int* bsum      = dst_sorted + Ee;          // 256
    int* gstart    = bsum + 256;               // G+1

    const int NB = 196;  // ceil(50000/256)
    hipMemsetAsync(deg, 0, Nn * sizeof(int), stream);
    k_hist<<<(Ee + 255) / 256, 256, 0, stream>>>(ei, deg);
    k_scan1<<<NB, 256, 0, stream>>>(deg, row_ptr, bsum);
    k_scan2<<<1, 256, 0, stream>>>(bsum, NB);
    k_scan3<<<(Nn + 256) / 256, 256, 0, stream>>>(row_ptr, bsum);
    hipMemcpyAsync(cursor, row_ptr, Nn * sizeof(int), hipMemcpyDeviceToDevice, stream);
    k_scatter<<<(Ee + 255) / 256, 256, 0, stream>>>(ei, cursor, src_perm, eperm, dst_sorted);
    k_gbound<<<(Nn + 255) / 256, 256, 0, stream>>>(bat, gstart);

    int nodeBlocks = (Nn + 63) / 64;
    k_encode<<<nodeBlocks, 256, 0, stream>>>(x, Wn, bn, h);
    for (int l = 0; l < 3; ++l) {
        k_wqm<<<1, 256, 0, stream>>>(Wq + l * 4096, bq + l * 64, We + l * 1024, Wqm, bqm);
        k_qkvt<<<nodeBlocks, 256, 0, stream>>>(h, Wq + l * 4096, bq + l * 64,
                                               Wk + l * 4096, bk + l * 64,
                                               Wv + l * 4096, bv + l * 64,
                                               Wqm, bqm, Wsk + l * 4096, bs + l * 64,
                                               qn, kn, vn, tq, sn);
        k_alpha<<<(Ee + 63) / 64, 256, 0, stream>>>(qn, kn, tq, src_perm, dst_sorted,
                                                    eperm, ea, alpha);
        k_agg<<<(Nn + 3) / 4, 256, 0, stream>>>(h, vn, sn, alpha, row_ptr, src_perm,
                                                eperm, ea, We + l * 1024);
    }
    k_pool<<<Gg, 256, 0, stream>>>(h, gstart, W1, b1, W2, b2, out);
}

// Round 5
// 4757.752 us; speedup vs baseline: 1.4677x; 1.4677x over previous
//
#include <hip/hip_runtime.h>
#include <math.h>

#define Nn 50000
#define Ee 1600000
#define Gg 64

// ---------------- one-time CSR build ----------------
__global__ void k_hist(const int* __restrict__ ei, int* __restrict__ deg) {
    int e = blockIdx.x * blockDim.x + threadIdx.x;
    if (e < Ee) atomicAdd(&deg[ei[Ee + e]], 1);
}

__global__ void k_scan1(const int* __restrict__ deg, int* __restrict__ row_ptr,
                        int* __restrict__ bsum) {
    __shared__ int buf[256];
    int i = blockIdx.x * 256 + threadIdx.x;
    int v = (i < Nn) ? deg[i] : 0;
    buf[threadIdx.x] = v;
    __syncthreads();
    for (int off = 1; off < 256; off <<= 1) {
        int t = (threadIdx.x >= off) ? buf[threadIdx.x - off] : 0;
        __syncthreads();
        buf[threadIdx.x] += t;
        __syncthreads();
    }
    if (i < Nn) row_ptr[i + 1] = buf[threadIdx.x];  // block-local inclusive
    if (threadIdx.x == 255) bsum[blockIdx.x] = buf[255];
}

__global__ void k_scan2(int* __restrict__ bsum, int nb) {
    __shared__ int buf[256];
    int v = (threadIdx.x < nb) ? bsum[threadIdx.x] : 0;
    buf[threadIdx.x] = v;
    __syncthreads();
    for (int off = 1; off < 256; off <<= 1) {
        int t = (threadIdx.x >= off) ? buf[threadIdx.x - off] : 0;
        __syncthreads();
        buf[threadIdx.x] += t;
        __syncthreads();
    }
    if (threadIdx.x < nb) bsum[threadIdx.x] = buf[threadIdx.x];  // inclusive
}

__global__ void k_scan3(int* __restrict__ row_ptr, const int* __restrict__ bsum) {
    int i = blockIdx.x * 256 + threadIdx.x;  // i in [0, Nn]
    if (i > Nn) return;
    if (i == 0) { row_ptr[0] = 0; return; }
    int b = (i - 1) >> 8;
    if (b > 0) row_ptr[i] += bsum[b - 1];
}

__global__ void k_scatter(const int* __restrict__ ei, int* __restrict__ cursor,
                          int* __restrict__ src_perm, int* __restrict__ eperm,
                          int* __restrict__ dst_sorted) {
    int e = blockIdx.x * blockDim.x + threadIdx.x;
    if (e >= Ee) return;
    int dst = ei[Ee + e];
    int pos = atomicAdd(&cursor[dst], 1);
    src_perm[pos] = ei[e];
    eperm[pos] = e;
    dst_sorted[pos] = dst;
}

__global__ void k_gbound(const int* __restrict__ batch, int* __restrict__ gstart) {
    int n = blockIdx.x * blockDim.x + threadIdx.x;
    if (n >= Nn) return;
    int b = batch[n];
    if (n == 0) { for (int g = 0; g <= b; ++g) gstart[g] = 0; }
    else { int bp = batch[n - 1]; for (int g = bp + 1; g <= b; ++g) gstart[g] = n; }
    if (n == Nn - 1) { for (int g = b + 1; g <= Gg; ++g) gstart[g] = Nn; }
}

// ---------------- node kernels ----------------
// h = relu(x @ Wn + bn). Register-blocked: x-tile in LDS, Wn chunk in regs.
// __launch_bounds__(256): block is 256; without it the compiler assumes 1024
// and caps VGPRs at 64 -> acc[] spills to scratch (R4: 2.9 GB/dispatch HBM).
__global__ __launch_bounds__(256) void k_encode(const float* __restrict__ x,
                         const float* __restrict__ Wn,
                         const float* __restrict__ bn, float* __restrict__ h) {
    __shared__ float sx[64 * 32];
    int base = blockIdx.x * 64;
    for (int i = threadIdx.x; i < 512; i += 256) {        // 64 rows x 32 cols, float4
        int off = i * 4, row = off >> 5;
        float4 v = (base + row < Nn) ? ((const float4*)(x))[(base * 32 + off) >> 2]
                                     : make_float4(0.f, 0.f, 0.f, 0.f);
        ((float4*)sx)[i] = v;
    }
    __syncthreads();
    int lane = threadIdx.x & 63, wv = threadIdx.x >> 6;
    float acc[16];
    float b = bn[lane];
#pragma unroll
    for (int nn = 0; nn < 16; ++nn) acc[nn] = b;
#pragma unroll
    for (int k0 = 0; k0 < 32; k0 += 4) {
        float w0 = Wn[(k0 + 0) * 64 + lane];
        float w1 = Wn[(k0 + 1) * 64 + lane];
        float w2 = Wn[(k0 + 2) * 64 + lane];
        float w3 = Wn[(k0 + 3) * 64 + lane];
#pragma unroll
        for (int nn = 0; nn < 16; ++nn) {
            int row = wv * 16 + nn;
            float4 hv = *(const float4*)&sx[row * 32 + k0];
            acc[nn] = fmaf(hv.x, w0, fmaf(hv.y, w1, fmaf(hv.z, w2, fmaf(hv.w, w3, acc[nn]))));
        }
    }
#pragma unroll
    for (int nn = 0; nn < 16; ++nn) {
        int n = base + wv * 16 + nn;
        if (n < Nn) h[(size_t)n * 64 + lane] = fmaxf(acc[nn], 0.f);
    }
}

// Wqm[j][l'=(h,i)] = sum_c Wq[j][h*16+c] * We[i][h*16+c];  bqm likewise from bq
__global__ void k_wqm(const float* __restrict__ Wq, const float* __restrict__ bq,
                      const float* __restrict__ We, float* __restrict__ Wqm,
                      float* __restrict__ bqm) {
    for (int o = threadIdx.x; o < 64 * 64; o += 256) {
        int j = o >> 6, lp = o & 63, hh = lp >> 4, ii = lp & 15;
        float acc = 0.f;
#pragma unroll
        for (int c = 0; c < 16; ++c)
            acc += Wq[j * 64 + hh * 16 + c] * We[ii * 64 + hh * 16 + c];
        Wqm[o] = acc;
    }
    if (threadIdx.x < 64) {
        int hh = threadIdx.x >> 4, ii = threadIdx.x & 15;
        float acc = 0.f;
#pragma unroll
        for (int c = 0; c < 16; ++c)
            acc += bq[hh * 16 + c] * We[ii * 64 + hh * 16 + c];
        bqm[threadIdx.x] = acc;
    }
}

// qn,kn,vn,tq,sn = h@{Wq,Wk,Wv,Wqm,Ws}+bias. Register-blocked 5-in-1 GEMM:
// h-tile (64x64) in LDS, weight k-chunk (4x5) in regs, acc[5][16] unrolled.
// __launch_bounds__(256) -> VGPR budget up to ~128/lane, no scratch spill.
__global__ __launch_bounds__(256) void k_qkvt(const float* __restrict__ h,
                       const float* __restrict__ Wq, const float* __restrict__ bq,
                       const float* __restrict__ Wk, const float* __restrict__ bk,
                       const float* __restrict__ Wv, const float* __restrict__ bv,
                       const float* __restrict__ Wqm, const float* __restrict__ bqm,
                       const float* __restrict__ Ws, const float* __restrict__ bs,
                       float* __restrict__ qn, float* __restrict__ kn,
                       float* __restrict__ vn, float* __restrict__ tq,
                       float* __restrict__ sn) {
    __shared__ float sh[64 * 64];
    int base = blockIdx.x * 64;
    for (int i = threadIdx.x; i < 1024; i += 256) {       // 64 rows x 64 cols, float4
        int off = i * 4, row = off >> 6;
        float4 v = (base + row < Nn) ? ((const float4*)(h))[((size_t)base * 64 + off) >> 2]
                                     : make_float4(0.f, 0.f, 0.f, 0.f);
        ((float4*)sh)[i] = v;
    }
    __syncthreads();
    int lane = threadIdx.x & 63, wv = threadIdx.x >> 6;
    float aq[16], ak[16], av[16], at[16], as_[16];
    float _bq = bq[lane], _bk = bk[lane], _bv = bv[lane], _bt = bqm[lane], _bs = bs[lane];
#pragma unroll
    for (int nn = 0; nn < 16; ++nn) {
        aq[nn] = _bq; ak[nn] = _bk; av[nn] = _bv; at[nn] = _bt; as_[nn] = _bs;
    }
#pragma unroll
    for (int k0 = 0; k0 < 64; k0 += 4) {
        float wq[4], wk[4], wvv[4], wt[4], ws[4];
#pragma unroll
        for (int j = 0; j < 4; ++j) {
            wq[j] = Wq[(k0 + j) * 64 + lane];
            wk[j] = Wk[(k0 + j) * 64 + lane];
            wvv[j] = Wv[(k0 + j) * 64 + lane];
            wt[j] = Wqm[(k0 + j) * 64 + lane];
            ws[j] = Ws[(k0 + j) * 64 + lane];
        }
#pragma unroll
        for (int nn = 0; nn < 16; ++nn) {
            int row = wv * 16 + nn;
            float4 hv = *(const float4*)&sh[row * 64 + k0];
            aq[nn] = fmaf(hv.x, wq[0], fmaf(hv.y, wq[1], fmaf(hv.z, wq[2], fmaf(hv.w, wq[3], aq[nn]))));
            ak[nn] = fmaf(hv.x, wk[0], fmaf(hv.y, wk[1], fmaf(hv.z, wk[2], fmaf(hv.w, wk[3], ak[nn]))));
            av[nn] = fmaf(hv.x, wvv[0], fmaf(hv.y, wvv[1], fmaf(hv.z, wvv[2], fmaf(hv.w, wvv[3], av[nn]))));
            at[nn] = fmaf(hv.x, wt[0], fmaf(hv.y, wt[1], fmaf(hv.z, wt[2], fmaf(hv.w, wt[3], at[nn]))));
            as_[nn] = fmaf(hv.x, ws[0], fmaf(hv.y, ws[1], fmaf(hv.z, ws[2], fmaf(hv.w, ws[3], as_[nn]))));
        }
    }
#pragma unroll
    for (int nn = 0; nn < 16; ++nn) {
        int n = base + wv * 16 + nn;
        if (n < Nn) {
            size_t o = (size_t)n * 64 + lane;
            qn[o] = aq[nn]; kn[o] = ak[nn]; vn[o] = av[nn]; tq[o] = at[nn]; sn[o] = as_[nn];
        }
    }
}

// edge-parallel, CSR order: alpha[idx][h] = 0.25*(q[d]·k[s] + ea[e]·tq[d])
__global__ void k_alpha(const float* __restrict__ qn, const float* __restrict__ kn,
                        const float* __restrict__ tq, const int* __restrict__ src_perm,
                        const int* __restrict__ dst_sorted, const int* __restrict__ eperm,
                        const float* __restrict__ ea, float* __restrict__ alpha) {
    __shared__ float ea_s[64 * 16];
    __shared__ float al_s[64 * 4];
    int base = blockIdx.x * 64;
    {   // stage 64 edges' ea rows (float4-coalesced gather)
        int t = threadIdx.x;
        int idx = base + (t >> 2);
        if (idx < Ee) {
            int e = eperm[idx];
            ((float4*)ea_s)[t] = ((const float4*)(ea + (size_t)e * 16))[t & 3];
        }
    }
    __syncthreads();
    int lane = threadIdx.x & 63, wv = threadIdx.x >> 6;
    int hh = lane >> 4, cc = lane & 15;
    for (int it = 0; it < 16; ++it) {
        int el = wv * 16 + it;
        int idx = base + el;
        if (idx < Ee) {
            int s = src_perm[idx], d = dst_sorted[idx];
            float q = qn[(size_t)d * 64 + lane];
            float k = kn[(size_t)s * 64 + lane];
            float t = tq[(size_t)d * 64 + lane];
            float part = q * k + ea_s[el * 16 + cc] * t;
            part += __shfl_xor(part, 1, 16);
            part += __shfl_xor(part, 2, 16);
            part += __shfl_xor(part, 4, 16);
            part += __shfl_xor(part, 8, 16);
            if (cc == 0) al_s[el * 4 + hh] = part * 0.25f;
        }
    }
    __syncthreads();
    {
        long gi = (long)base * 4 + threadIdx.x;
        if (gi < (long)Ee * 4) alpha[gi] = al_s[threadIdx.x];
    }
}

// node-parallel aggregation: max sweep + 4-way-unrolled weighted sums, then
// (acce)@We transform + skip + relu + residual. No atomics.
__global__ void k_agg(float* __restrict__ h, const float* __restrict__ vn,
                      const float* __restrict__ sn, const float* __restrict__ alpha,
                      const int* __restrict__ row_ptr, const int* __restrict__ src_perm,
                      const int* __restrict__ eperm, const float* __restrict__ ea,
                      const float* __restrict__ We) {
    __shared__ float sWe[1024];
    __shared__ float tile[4][64];
    for (int t = threadIdx.x; t < 1024; t += 256) sWe[t] = We[t];
    __syncthreads();
    int lane = threadIdx.x & 63, wv = threadIdx.x >> 6;
    int hh = lane >> 4, cc = lane & 15;
    int n = blockIdx.x * 4 + wv;
    if (n >= Nn) return;
    int beg = row_ptr[n], end = row_ptr[n + 1];
    // sweep 1: per-head max (coalesced: 64 lanes cover 16 edges x 4 heads)
    float vm = -INFINITY;
    for (int b = beg; b < end; b += 16) {
        int j = b + cc;
        if (j < end) vm = fmaxf(vm, alpha[(size_t)j * 4 + hh]);
    }
    vm = fmaxf(vm, __shfl_xor(vm, 1, 16));
    vm = fmaxf(vm, __shfl_xor(vm, 2, 16));
    vm = fmaxf(vm, __shfl_xor(vm, 4, 16));
    vm = fmaxf(vm, __shfl_xor(vm, 8, 16));
    // sweep 2: weighted accumulation, 4 edges in flight
    float accv = 0.f, acce = 0.f, accd = 0.f;
    int idx = beg;
    for (; idx + 4 <= end; idx += 4) {
        int s0 = src_perm[idx], s1 = src_perm[idx + 1], s2 = src_perm[idx + 2], s3 = src_perm[idx + 3];
        int e0 = eperm[idx], e1 = eperm[idx + 1], e2 = eperm[idx + 2], e3 = eperm[idx + 3];
        float a0 = alpha[(size_t)idx * 4 + hh], a1 = alpha[(size_t)(idx + 1) * 4 + hh];
        float a2 = alpha[(size_t)(idx + 2) * 4 + hh], a3 = alpha[(size_t)(idx + 3) * 4 + hh];
        float v0 = vn[(size_t)s0 * 64 + lane], v1 = vn[(size_t)s1 * 64 + lane];
        float v2 = vn[(size_t)s2 * 64 + lane], v3 = vn[(size_t)s3 * 64 + lane];
        float x0 = ea[(size_t)e0 * 16 + cc], x1 = ea[(size_t)e1 * 16 + cc];
        float x2 = ea[(size_t)e2 * 16 + cc], x3 = ea[(size_t)e3 * 16 + cc];
        float p0 = __expf(a0 - vm), p1 = __expf(a1 - vm);
        float p2 = __expf(a2 - vm), p3 = __expf(a3 - vm);
        accd += (p0 + p1) + (p2 + p3);
        accv = fmaf(p0, v0, fmaf(p1, v1, fmaf(p2, v2, fmaf(p3, v3, accv))));
        acce = fmaf(p0, x0, fmaf(p1, x1, fmaf(p2, x2, fmaf(p3, x3, acce))));
    }
    for (; idx < end; ++idx) {
        int s0 = src_perm[idx], e0 = eperm[idx];
        float p0 = __expf(alpha[(size_t)idx * 4 + hh] - vm);
        accd += p0;
        accv = fmaf(p0, vn[(size_t)s0 * 64 + lane], accv);
        acce = fmaf(p0, ea[(size_t)e0 * 16 + cc], acce);
    }
    float inv = 1.f / (accd + 1e-16f);
    tile[wv][lane] = acce * inv;  // (h,i) layout, wave-local LDS (no barrier needed)
    float re = 0.f;
#pragma unroll
    for (int i = 0; i < 16; ++i)
        re = fmaf(tile[wv][hh * 16 + i], sWe[i * 64 + lane], re);
    size_t o = (size_t)n * 64 + lane;
    float hv = h[o];
    h[o] = hv + fmaxf(accv * inv + re + sn[o], 0.f);
}

// mean-pool per group (batch sorted -> boundaries) + fused MLP head
__global__ void k_pool(const float* __restrict__ h, const int* __restrict__ gstart,
                       const float* __restrict__ W1, const float* __restrict__ b1,
                       const float* __restrict__ W2, const float* __restrict__ b2,
                       float* __restrict__ out) {
    int g = blockIdx.x;
    int lane = threadIdx.x & 63, wv = threadIdx.x >> 6;
    int beg = gstart[g], end = gstart[g + 1];
    __shared__ float red[4][64];
    __shared__ float sp[64];
    __shared__ float sh[32];
    float acc = 0.f;
    for (int n = beg + wv; n < end; n += 4) acc += h[(size_t)n * 64 + lane];
    red[wv][lane] = acc;
    __syncthreads();
    if (threadIdx.x < 64) {
        float c = fmaxf((float)(end - beg), 1.f);
        sp[lane] = (red[0][lane] + red[1][lane] + red[2][lane] + red[3][lane]) / c;
    }
    __syncthreads();
    if (threadIdx.x < 32) {
        int t = threadIdx.x;
        float a = b1[t];
#pragma unroll
        for (int i = 0; i < 64; ++i) a = fmaf(sp[i], W1[i * 32 + t], a);
        sh[t] = fmaxf(a, 0.f) * W2[t];
    }
    __syncthreads();
    if (threadIdx.x == 0) {
        float s = b2[0];
#pragma unroll
        for (int i = 0; i < 32; ++i) s += sh[i];
        out[g] = s;
    }
}

extern "C" void kernel_launch(void* const* d_in, const int* in_sizes, int n_in,
                              void* d_out, int out_size, void* d_ws, size_t ws_size,
                              hipStream_t stream) {
    const float* x   = (const float*)d_in[0];
    const int*   ei  = (const int*)d_in[1];
    const float* ea  = (const float*)d_in[2];
    const int*   bat = (const int*)d_in[3];
    const float* Wn  = (const float*)d_in[4];
    const float* bn  = (const float*)d_in[5];
    const float* Wq  = (const float*)d_in[6];
    const float* bq  = (const float*)d_in[7];
    const float* Wk  = (const float*)d_in[8];
    const float* bk  = (const float*)d_in[9];
    const float* Wv  = (const float*)d_in[10];
    const float* bv  = (const float*)d_in[11];
    const float* We  = (const float*)d_in[12];
    const float* Wsk = (const float*)d_in[13];
    const float* bs  = (const float*)d_in[14];
    const float* W1  = (const float*)d_in[15];
    const float* b1  = (const float*)d_in[16];
    const float* W2  = (const float*)d_in[17];
    const float* b2  = (const float*)d_in[18];
    float* out = (float*)d_out;

    const size_t NH = (size_t)Nn * 64;
    float* h    = (float*)d_ws;
    float* qn   = h + NH;
    float* kn   = h + 2 * NH;
    float* vn   = h + 3 * NH;
    float* tq   = h + 4 * NH;
    float* sn   = h + 5 * NH;
    float* alpha = h + 6 * NH;                 // E*4
    float* Wqm  = alpha + (size_t)Ee * 4;      // 4096
    float* bqm  = Wqm + 4096;                  // 64
    int* deg       = (int*)(bqm + 64);         // N
    int* row_ptr   = deg + Nn;                 // N+1
    int* cursor    = row_ptr + Nn + 1;         // N
    int* src_perm  = cursor + Nn;              // E
    int* eperm     = src_perm + Ee;            // E
    int* dst_sorted = eperm + Ee;              // E
    int* bsum      = dst_sorted + Ee;          // 256
    int* gstart    = bsum + 256;               // G+1

    const int NB = 196;  // ceil(50000/256)
    hipMemsetAsync(deg, 0, Nn * sizeof(int), stream);
    k_hist<<<(Ee + 255) / 256, 256, 0, stream>>>(ei, deg);
    k_scan1<<<NB, 256, 0, stream>>>(deg, row_ptr, bsum);
    k_scan2<<<1, 256, 0, stream>>>(bsum, NB);
    k_scan3<<<(Nn + 256) / 256, 256, 0, stream>>>(row_ptr, bsum);
    hipMemcpyAsync(cursor, row_ptr, Nn * sizeof(int), hipMemcpyDeviceToDevice, stream);
    k_scatter<<<(Ee + 255) / 256, 256, 0, stream>>>(ei, cursor, src_perm, eperm, dst_sorted);
    k_gbound<<<(Nn + 255) / 256, 256, 0, stream>>>(bat, gstart);

    int nodeBlocks = (Nn + 63) / 64;
    k_encode<<<nodeBlocks, 256, 0, stream>>>(x, Wn, bn, h);
    for (int l = 0; l < 3; ++l) {
        k_wqm<<<1, 256, 0, stream>>>(Wq + l * 4096, bq + l * 64, We + l * 1024, Wqm, bqm);
        k_qkvt<<<nodeBlocks, 256, 0, stream>>>(h, Wq + l * 4096, bq + l * 64,
                                               Wk + l * 4096, bk + l * 64,
                                               Wv + l * 4096, bv + l * 64,
                                               Wqm, bqm, Wsk + l * 4096, bs + l * 64,
                                               qn, kn, vn, tq, sn);
        k_alpha<<<(Ee + 63) / 64, 256, 0, stream>>>(qn, kn, tq, src_perm, dst_sorted,
                                                    eperm, ea, alpha);
        k_agg<<<(Nn + 3) / 4, 256, 0, stream>>>(h, vn, sn, alpha, row_ptr, src_perm,
                                                eperm, ea, We + l * 1024);
    }
    k_pool<<<Gg, 256, 0, stream>>>(h, gstart, W1, b1, W2, b2, out);
}

// Round 6
// 1551.256 us; speedup vs baseline: 4.5015x; 3.0670x over previous
//
#include <hip/hip_runtime.h>
#include <math.h>

#define Nn 50000
#define Ee 1600000
#define Gg 64

// ---------------- one-time CSR build ----------------
__global__ void k_hist(const int* __restrict__ ei, int* __restrict__ deg) {
    int e = blockIdx.x * blockDim.x + threadIdx.x;
    if (e < Ee) atomicAdd(&deg[ei[Ee + e]], 1);
}

__global__ void k_scan1(const int* __restrict__ deg, int* __restrict__ row_ptr,
                        int* __restrict__ bsum) {
    __shared__ int buf[256];
    int i = blockIdx.x * 256 + threadIdx.x;
    int v = (i < Nn) ? deg[i] : 0;
    buf[threadIdx.x] = v;
    __syncthreads();
    for (int off = 1; off < 256; off <<= 1) {
        int t = (threadIdx.x >= off) ? buf[threadIdx.x - off] : 0;
        __syncthreads();
        buf[threadIdx.x] += t;
        __syncthreads();
    }
    if (i < Nn) row_ptr[i + 1] = buf[threadIdx.x];  // block-local inclusive
    if (threadIdx.x == 255) bsum[blockIdx.x] = buf[255];
}

__global__ void k_scan2(int* __restrict__ bsum, int nb) {
    __shared__ int buf[256];
    int v = (threadIdx.x < nb) ? bsum[threadIdx.x] : 0;
    buf[threadIdx.x] = v;
    __syncthreads();
    for (int off = 1; off < 256; off <<= 1) {
        int t = (threadIdx.x >= off) ? buf[threadIdx.x - off] : 0;
        __syncthreads();
        buf[threadIdx.x] += t;
        __syncthreads();
    }
    if (threadIdx.x < nb) bsum[threadIdx.x] = buf[threadIdx.x];  // inclusive
}

__global__ void k_scan3(int* __restrict__ row_ptr, const int* __restrict__ bsum) {
    int i = blockIdx.x * 256 + threadIdx.x;  // i in [0, Nn]
    if (i > Nn) return;
    if (i == 0) { row_ptr[0] = 0; return; }
    int b = (i - 1) >> 8;
    if (b > 0) row_ptr[i] += bsum[b - 1];
}

__global__ void k_scatter(const int* __restrict__ ei, int* __restrict__ cursor,
                          int* __restrict__ src_perm, int* __restrict__ eperm,
                          int* __restrict__ dst_sorted) {
    int e = blockIdx.x * blockDim.x + threadIdx.x;
    if (e >= Ee) return;
    int dst = ei[Ee + e];
    int pos = atomicAdd(&cursor[dst], 1);
    src_perm[pos] = ei[e];
    eperm[pos] = e;
    dst_sorted[pos] = dst;
}

__global__ void k_gbound(const int* __restrict__ batch, int* __restrict__ gstart) {
    int n = blockIdx.x * blockDim.x + threadIdx.x;
    if (n >= Nn) return;
    int b = batch[n];
    if (n == 0) { for (int g = 0; g <= b; ++g) gstart[g] = 0; }
    else { int bp = batch[n - 1]; for (int g = bp + 1; g <= b; ++g) gstart[g] = n; }
    if (n == Nn - 1) { for (int g = b + 1; g <= Gg; ++g) gstart[g] = Nn; }
}

// ---------------- node kernels ----------------
// h = relu(x @ Wn + bn). Register-blocked: x-tile in LDS, Wn chunk in regs.
// NOTE: k0 loop must NOT be unrolled — full unroll exposes all weight loads
// at once, the scheduler hoists them, live range explodes -> scratch spill
// (R4/R5: 0.6-2.9 GB/dispatch scratch traffic).
__global__ __launch_bounds__(256) void k_encode(const float* __restrict__ x,
                         const float* __restrict__ Wn,
                         const float* __restrict__ bn, float* __restrict__ h) {
    __shared__ float sx[64 * 32];
    int base = blockIdx.x * 64;
    for (int i = threadIdx.x; i < 512; i += 256) {        // 64 rows x 32 cols, float4
        int off = i * 4, row = off >> 5;
        float4 v = (base + row < Nn) ? ((const float4*)(x))[(base * 32 + off) >> 2]
                                     : make_float4(0.f, 0.f, 0.f, 0.f);
        ((float4*)sx)[i] = v;
    }
    __syncthreads();
    int lane = threadIdx.x & 63, wv = threadIdx.x >> 6;
    float acc[16];
    float b = bn[lane];
#pragma unroll
    for (int nn = 0; nn < 16; ++nn) acc[nn] = b;
#pragma unroll 1
    for (int k0 = 0; k0 < 32; k0 += 4) {
        float w0 = Wn[(k0 + 0) * 64 + lane];
        float w1 = Wn[(k0 + 1) * 64 + lane];
        float w2 = Wn[(k0 + 2) * 64 + lane];
        float w3 = Wn[(k0 + 3) * 64 + lane];
#pragma unroll
        for (int nn = 0; nn < 16; ++nn) {
            int row = wv * 16 + nn;
            float4 hv = *(const float4*)&sx[row * 32 + k0];
            acc[nn] = fmaf(hv.x, w0, fmaf(hv.y, w1, fmaf(hv.z, w2, fmaf(hv.w, w3, acc[nn]))));
        }
    }
#pragma unroll
    for (int nn = 0; nn < 16; ++nn) {
        int n = base + wv * 16 + nn;
        if (n < Nn) h[(size_t)n * 64 + lane] = fmaxf(acc[nn], 0.f);
    }
}

// Wqm[j][l'=(h,i)] = sum_c Wq[j][h*16+c] * We[i][h*16+c];  bqm likewise from bq
__global__ void k_wqm(const float* __restrict__ Wq, const float* __restrict__ bq,
                      const float* __restrict__ We, float* __restrict__ Wqm,
                      float* __restrict__ bqm) {
    for (int o = threadIdx.x; o < 64 * 64; o += 256) {
        int j = o >> 6, lp = o & 63, hh = lp >> 4, ii = lp & 15;
        float acc = 0.f;
#pragma unroll
        for (int c = 0; c < 16; ++c)
            acc += Wq[j * 64 + hh * 16 + c] * We[ii * 64 + hh * 16 + c];
        Wqm[o] = acc;
    }
    if (threadIdx.x < 64) {
        int hh = threadIdx.x >> 4, ii = threadIdx.x & 15;
        float acc = 0.f;
#pragma unroll
        for (int c = 0; c < 16; ++c)
            acc += bq[hh * 16 + c] * We[ii * 64 + hh * 16 + c];
        bqm[threadIdx.x] = acc;
    }
}

// qn,kn,vn,tq,sn = h@{Wq,Wk,Wv,Wqm,Ws}+bias. Register-blocked 5-in-1 GEMM:
// h-tile (64x64) in LDS, weight k-chunk (4x5=20 regs) in regs, acc[5][16]=80.
// k0 loop sequential (unroll 1) -> live set ~130 VGPRs, no spill.
__global__ __launch_bounds__(256) void k_qkvt(const float* __restrict__ h,
                       const float* __restrict__ Wq, const float* __restrict__ bq,
                       const float* __restrict__ Wk, const float* __restrict__ bk,
                       const float* __restrict__ Wv, const float* __restrict__ bv,
                       const float* __restrict__ Wqm, const float* __restrict__ bqm,
                       const float* __restrict__ Ws, const float* __restrict__ bs,
                       float* __restrict__ qn, float* __restrict__ kn,
                       float* __restrict__ vn, float* __restrict__ tq,
                       float* __restrict__ sn) {
    __shared__ float sh[64 * 64];
    int base = blockIdx.x * 64;
    for (int i = threadIdx.x; i < 1024; i += 256) {       // 64 rows x 64 cols, float4
        int off = i * 4, row = off >> 6;
        float4 v = (base + row < Nn) ? ((const float4*)(h))[((size_t)base * 64 + off) >> 2]
                                     : make_float4(0.f, 0.f, 0.f, 0.f);
        ((float4*)sh)[i] = v;
    }
    __syncthreads();
    int lane = threadIdx.x & 63, wv = threadIdx.x >> 6;
    float aq[16], ak[16], av[16], at[16], as_[16];
    float _bq = bq[lane], _bk = bk[lane], _bv = bv[lane], _bt = bqm[lane], _bs = bs[lane];
#pragma unroll
    for (int nn = 0; nn < 16; ++nn) {
        aq[nn] = _bq; ak[nn] = _bk; av[nn] = _bv; at[nn] = _bt; as_[nn] = _bs;
    }
#pragma unroll 1
    for (int k0 = 0; k0 < 64; k0 += 4) {
        float wq[4], wk[4], wvv[4], wt[4], ws[4];
#pragma unroll
        for (int j = 0; j < 4; ++j) {
            wq[j] = Wq[(k0 + j) * 64 + lane];
            wk[j] = Wk[(k0 + j) * 64 + lane];
            wvv[j] = Wv[(k0 + j) * 64 + lane];
            wt[j] = Wqm[(k0 + j) * 64 + lane];
            ws[j] = Ws[(k0 + j) * 64 + lane];
        }
#pragma unroll
        for (int nn = 0; nn < 16; ++nn) {
            int row = wv * 16 + nn;
            float4 hv = *(const float4*)&sh[row * 64 + k0];
            aq[nn] = fmaf(hv.x, wq[0], fmaf(hv.y, wq[1], fmaf(hv.z, wq[2], fmaf(hv.w, wq[3], aq[nn]))));
            ak[nn] = fmaf(hv.x, wk[0], fmaf(hv.y, wk[1], fmaf(hv.z, wk[2], fmaf(hv.w, wk[3], ak[nn]))));
            av[nn] = fmaf(hv.x, wvv[0], fmaf(hv.y, wvv[1], fmaf(hv.z, wvv[2], fmaf(hv.w, wvv[3], av[nn]))));
            at[nn] = fmaf(hv.x, wt[0], fmaf(hv.y, wt[1], fmaf(hv.z, wt[2], fmaf(hv.w, wt[3], at[nn]))));
            as_[nn] = fmaf(hv.x, ws[0], fmaf(hv.y, ws[1], fmaf(hv.z, ws[2], fmaf(hv.w, ws[3], as_[nn]))));
        }
    }
#pragma unroll
    for (int nn = 0; nn < 16; ++nn) {
        int n = base + wv * 16 + nn;
        if (n < Nn) {
            size_t o = (size_t)n * 64 + lane;
            qn[o] = aq[nn]; kn[o] = ak[nn]; vn[o] = av[nn]; tq[o] = at[nn]; sn[o] = as_[nn];
        }
    }
}

// edge-parallel, CSR order: alpha[idx][h] = 0.25*(q[d]·k[s] + ea[e]·tq[d])
__global__ void k_alpha(const float* __restrict__ qn, const float* __restrict__ kn,
                        const float* __restrict__ tq, const int* __restrict__ src_perm,
                        const int* __restrict__ dst_sorted, const int* __restrict__ eperm,
                        const float* __restrict__ ea, float* __restrict__ alpha) {
    __shared__ float ea_s[64 * 16];
    __shared__ float al_s[64 * 4];
    int base = blockIdx.x * 64;
    {   // stage 64 edges' ea rows (float4-coalesced gather)
        int t = threadIdx.x;
        int idx = base + (t >> 2);
        if (idx < Ee) {
            int e = eperm[idx];
            ((float4*)ea_s)[t] = ((const float4*)(ea + (size_t)e * 16))[t & 3];
        }
    }
    __syncthreads();
    int lane = threadIdx.x & 63, wv = threadIdx.x >> 6;
    int hh = lane >> 4, cc = lane & 15;
    for (int it = 0; it < 16; ++it) {
        int el = wv * 16 + it;
        int idx = base + el;
        if (idx < Ee) {
            int s = src_perm[idx], d = dst_sorted[idx];
            float q = qn[(size_t)d * 64 + lane];
            float k = kn[(size_t)s * 64 + lane];
            float t = tq[(size_t)d * 64 + lane];
            float part = q * k + ea_s[el * 16 + cc] * t;
            part += __shfl_xor(part, 1, 16);
            part += __shfl_xor(part, 2, 16);
            part += __shfl_xor(part, 4, 16);
            part += __shfl_xor(part, 8, 16);
            if (cc == 0) al_s[el * 4 + hh] = part * 0.25f;
        }
    }
    __syncthreads();
    {
        long gi = (long)base * 4 + threadIdx.x;
        if (gi < (long)Ee * 4) alpha[gi] = al_s[threadIdx.x];
    }
}

// node-parallel aggregation: max sweep + 4-way-unrolled weighted sums, then
// (acce)@We transform + skip + relu + residual. No atomics.
__global__ void k_agg(float* __restrict__ h, const float* __restrict__ vn,
                      const float* __restrict__ sn, const float* __restrict__ alpha,
                      const int* __restrict__ row_ptr, const int* __restrict__ src_perm,
                      const int* __restrict__ eperm, const float* __restrict__ ea,
                      const float* __restrict__ We) {
    __shared__ float sWe[1024];
    __shared__ float tile[4][64];
    for (int t = threadIdx.x; t < 1024; t += 256) sWe[t] = We[t];
    __syncthreads();
    int lane = threadIdx.x & 63, wv = threadIdx.x >> 6;
    int hh = lane >> 4, cc = lane & 15;
    int n = blockIdx.x * 4 + wv;
    if (n >= Nn) return;
    int beg = row_ptr[n], end = row_ptr[n + 1];
    // sweep 1: per-head max (coalesced: 64 lanes cover 16 edges x 4 heads)
    float vm = -INFINITY;
    for (int b = beg; b < end; b += 16) {
        int j = b + cc;
        if (j < end) vm = fmaxf(vm, alpha[(size_t)j * 4 + hh]);
    }
    vm = fmaxf(vm, __shfl_xor(vm, 1, 16));
    vm = fmaxf(vm, __shfl_xor(vm, 2, 16));
    vm = fmaxf(vm, __shfl_xor(vm, 4, 16));
    vm = fmaxf(vm, __shfl_xor(vm, 8, 16));
    // sweep 2: weighted accumulation, 4 edges in flight
    float accv = 0.f, acce = 0.f, accd = 0.f;
    int idx = beg;
    for (; idx + 4 <= end; idx += 4) {
        int s0 = src_perm[idx], s1 = src_perm[idx + 1], s2 = src_perm[idx + 2], s3 = src_perm[idx + 3];
        int e0 = eperm[idx], e1 = eperm[idx + 1], e2 = eperm[idx + 2], e3 = eperm[idx + 3];
        float a0 = alpha[(size_t)idx * 4 + hh], a1 = alpha[(size_t)(idx + 1) * 4 + hh];
        float a2 = alpha[(size_t)(idx + 2) * 4 + hh], a3 = alpha[(size_t)(idx + 3) * 4 + hh];
        float v0 = vn[(size_t)s0 * 64 + lane], v1 = vn[(size_t)s1 * 64 + lane];
        float v2 = vn[(size_t)s2 * 64 + lane], v3 = vn[(size_t)s3 * 64 + lane];
        float x0 = ea[(size_t)e0 * 16 + cc], x1 = ea[(size_t)e1 * 16 + cc];
        float x2 = ea[(size_t)e2 * 16 + cc], x3 = ea[(size_t)e3 * 16 + cc];
        float p0 = __expf(a0 - vm), p1 = __expf(a1 - vm);
        float p2 = __expf(a2 - vm), p3 = __expf(a3 - vm);
        accd += (p0 + p1) + (p2 + p3);
        accv = fmaf(p0, v0, fmaf(p1, v1, fmaf(p2, v2, fmaf(p3, v3, accv))));
        acce = fmaf(p0, x0, fmaf(p1, x1, fmaf(p2, x2, fmaf(p3, x3, acce))));
    }
    for (; idx < end; ++idx) {
        int s0 = src_perm[idx], e0 = eperm[idx];
        float p0 = __expf(alpha[(size_t)idx * 4 + hh] - vm);
        accd += p0;
        accv = fmaf(p0, vn[(size_t)s0 * 64 + lane], accv);
        acce = fmaf(p0, ea[(size_t)e0 * 16 + cc], acce);
    }
    float inv = 1.f / (accd + 1e-16f);
    tile[wv][lane] = acce * inv;  // (h,i) layout, wave-local LDS (no barrier needed)
    float re = 0.f;
#pragma unroll
    for (int i = 0; i < 16; ++i)
        re = fmaf(tile[wv][hh * 16 + i], sWe[i * 64 + lane], re);
    size_t o = (size_t)n * 64 + lane;
    float hv = h[o];
    h[o] = hv + fmaxf(accv * inv + re + sn[o], 0.f);
}

// mean-pool per group (batch sorted -> boundaries) + fused MLP head
__global__ void k_pool(const float* __restrict__ h, const int* __restrict__ gstart,
                       const float* __restrict__ W1, const float* __restrict__ b1,
                       const float* __restrict__ W2, const float* __restrict__ b2,
                       float* __restrict__ out) {
    int g = blockIdx.x;
    int lane = threadIdx.x & 63, wv = threadIdx.x >> 6;
    int beg = gstart[g], end = gstart[g + 1];
    __shared__ float red[4][64];
    __shared__ float sp[64];
    __shared__ float sh[32];
    float acc = 0.f;
    for (int n = beg + wv; n < end; n += 4) acc += h[(size_t)n * 64 + lane];
    red[wv][lane] = acc;
    __syncthreads();
    if (threadIdx.x < 64) {
        float c = fmaxf((float)(end - beg), 1.f);
        sp[lane] = (red[0][lane] + red[1][lane] + red[2][lane] + red[3][lane]) / c;
    }
    __syncthreads();
    if (threadIdx.x < 32) {
        int t = threadIdx.x;
        float a = b1[t];
#pragma unroll
        for (int i = 0; i < 64; ++i) a = fmaf(sp[i], W1[i * 32 + t], a);
        sh[t] = fmaxf(a, 0.f) * W2[t];
    }
    __syncthreads();
    if (threadIdx.x == 0) {
        float s = b2[0];
#pragma unroll
        for (int i = 0; i < 32; ++i) s += sh[i];
        out[g] = s;
    }
}

extern "C" void kernel_launch(void* const* d_in, const int* in_sizes, int n_in,
                              void* d_out, int out_size, void* d_ws, size_t ws_size,
                              hipStream_t stream) {
    const float* x   = (const float*)d_in[0];
    const int*   ei  = (const int*)d_in[1];
    const float* ea  = (const float*)d_in[2];
    const int*   bat = (const int*)d_in[3];
    const float* Wn  = (const float*)d_in[4];
    const float* bn  = (const float*)d_in[5];
    const float* Wq  = (const float*)d_in[6];
    const float* bq  = (const float*)d_in[7];
    const float* Wk  = (const float*)d_in[8];
    const float* bk  = (const float*)d_in[9];
    const float* Wv  = (const float*)d_in[10];
    const float* bv  = (const float*)d_in[11];
    const float* We  = (const float*)d_in[12];
    const float* Wsk = (const float*)d_in[13];
    const float* bs  = (const float*)d_in[14];
    const float* W1  = (const float*)d_in[15];
    const float* b1  = (const float*)d_in[16];
    const float* W2  = (const float*)d_in[17];
    const float* b2  = (const float*)d_in[18];
    float* out = (float*)d_out;

    const size_t NH = (size_t)Nn * 64;
    float* h    = (float*)d_ws;
    float* qn   = h + NH;
    float* kn   = h + 2 * NH;
    float* vn   = h + 3 * NH;
    float* tq   = h + 4 * NH;
    float* sn   = h + 5 * NH;
    float* alpha = h + 6 * NH;                 // E*4
    float* Wqm  = alpha + (size_t)Ee * 4;      // 4096
    float* bqm  = Wqm + 4096;                  // 64
    int* deg       = (int*)(bqm + 64);         // N
    int* row_ptr   = deg + Nn;                 // N+1
    int* cursor    = row_ptr + Nn + 1;         // N
    int* src_perm  = cursor + Nn;              // E
    int* eperm     = src_perm + Ee;            // E
    int* dst_sorted = eperm + Ee;              // E
    int* bsum      = dst_sorted + Ee;          // 256
    int* gstart    = bsum + 256;               // G+1

    const int NB = 196;  // ceil(50000/256)
    hipMemsetAsync(deg, 0, Nn * sizeof(int), stream);
    k_hist<<<(Ee + 255) / 256, 256, 0, stream>>>(ei, deg);
    k_scan1<<<NB, 256, 0, stream>>>(deg, row_ptr, bsum);
    k_scan2<<<1, 256, 0, stream>>>(bsum, NB);
    k_scan3<<<(Nn + 256) / 256, 256, 0, stream>>>(row_ptr, bsum);
    hipMemcpyAsync(cursor, row_ptr, Nn * sizeof(int), hipMemcpyDeviceToDevice, stream);
    k_scatter<<<(Ee + 255) / 256, 256, 0, stream>>>(ei, cursor, src_perm, eperm, dst_sorted);
    k_gbound<<<(Nn + 255) / 256, 256, 0, stream>>>(bat, gstart);

    int nodeBlocks = (Nn + 63) / 64;
    k_encode<<<nodeBlocks, 256, 0, stream>>>(x, Wn, bn, h);
    for (int l = 0; l < 3; ++l) {
        k_wqm<<<1, 256, 0, stream>>>(Wq + l * 4096, bq + l * 64, We + l * 1024, Wqm, bqm);
        k_qkvt<<<nodeBlocks, 256, 0, stream>>>(h, Wq + l * 4096, bq + l * 64,
                                               Wk + l * 4096, bk + l * 64,
                                               Wv + l * 4096, bv + l * 64,
                                               Wqm, bqm, Wsk + l * 4096, bs + l * 64,
                                               qn, kn, vn, tq, sn);
        k_alpha<<<(Ee + 63) / 64, 256, 0, stream>>>(qn, kn, tq, src_perm, dst_sorted,
                                                    eperm, ea, alpha);
        k_agg<<<(Nn + 3) / 4, 256, 0, stream>>>(h, vn, sn, alpha, row_ptr, src_perm,
                                                eperm, ea, We + l * 1024);
    }
    k_pool<<<Gg, 256, 0, stream>>>(h, gstart, W1, b1, W2, b2, out);
}

// Round 8
// 1017.922 us; speedup vs baseline: 6.8600x; 1.5239x over previous
//
#include <hip/hip_runtime.h>

#define Nn 50000
#define Ee 1600000
#define Gg 64

// ---------------- one-time CSR build ----------------
__global__ void k_hist(const int* __restrict__ ei, int* __restrict__ deg) {
    int e = blockIdx.x * blockDim.x + threadIdx.x;
    if (e < Ee) atomicAdd(&deg[ei[Ee + e]], 1);
}

__global__ void k_scan1(const int* __restrict__ deg, int* __restrict__ row_ptr,
                        int* __restrict__ bsum) {
    __shared__ int buf[256];
    int i = blockIdx.x * 256 + threadIdx.x;
    int v = (i < Nn) ? deg[i] : 0;
    buf[threadIdx.x] = v;
    __syncthreads();
    for (int off = 1; off < 256; off <<= 1) {
        int t = (threadIdx.x >= off) ? buf[threadIdx.x - off] : 0;
        __syncthreads();
        buf[threadIdx.x] += t;
        __syncthreads();
    }
    if (i < Nn) row_ptr[i + 1] = buf[threadIdx.x];  // block-local inclusive
    if (threadIdx.x == 255) bsum[blockIdx.x] = buf[255];
}

__global__ void k_scan2(int* __restrict__ bsum, int nb) {
    __shared__ int buf[256];
    int v = (threadIdx.x < nb) ? bsum[threadIdx.x] : 0;
    buf[threadIdx.x] = v;
    __syncthreads();
    for (int off = 1; off < 256; off <<= 1) {
        int t = (threadIdx.x >= off) ? buf[threadIdx.x - off] : 0;
        __syncthreads();
        buf[threadIdx.x] += t;
        __syncthreads();
    }
    if (threadIdx.x < nb) bsum[threadIdx.x] = buf[threadIdx.x];  // inclusive
}

__global__ void k_scan3(int* __restrict__ row_ptr, const int* __restrict__ bsum) {
    int i = blockIdx.x * 256 + threadIdx.x;  // i in [0, Nn]
    if (i > Nn) return;
    if (i == 0) { row_ptr[0] = 0; return; }
    int b = (i - 1) >> 8;
    if (b > 0) row_ptr[i] += bsum[b - 1];
}

__global__ void k_scatter(const int* __restrict__ ei, int* __restrict__ cursor,
                          int* __restrict__ src_perm, int* __restrict__ eperm) {
    int e = blockIdx.x * blockDim.x + threadIdx.x;
    if (e >= Ee) return;
    int dst = ei[Ee + e];
    int pos = atomicAdd(&cursor[dst], 1);
    src_perm[pos] = ei[e];
    eperm[pos] = e;
}

__global__ void k_gbound(const int* __restrict__ batch, int* __restrict__ gstart) {
    int n = blockIdx.x * blockDim.x + threadIdx.x;
    if (n >= Nn) return;
    int b = batch[n];
    if (n == 0) { for (int g = 0; g <= b; ++g) gstart[g] = 0; }
    else { int bp = batch[n - 1]; for (int g = bp + 1; g <= b; ++g) gstart[g] = n; }
    if (n == Nn - 1) { for (int g = b + 1; g <= Gg; ++g) gstart[g] = Nn; }
}

// ---------------- node kernels ----------------
// h = relu(x @ Wn + bn). Register-blocked: x-tile in LDS, Wn chunk in regs.
// k0 loop NOT unrolled (full unroll -> load hoisting -> spill, see R4/R5).
__global__ __launch_bounds__(256) void k_encode(const float* __restrict__ x,
                         const float* __restrict__ Wn,
                         const float* __restrict__ bn, float* __restrict__ h) {
    __shared__ float sx[64 * 32];
    int base = blockIdx.x * 64;
    for (int i = threadIdx.x; i < 512; i += 256) {        // 64 rows x 32 cols, float4
        int off = i * 4, row = off >> 5;
        float4 v = (base + row < Nn) ? ((const float4*)(x))[(base * 32 + off) >> 2]
                                     : make_float4(0.f, 0.f, 0.f, 0.f);
        ((float4*)sx)[i] = v;
    }
    __syncthreads();
    int lane = threadIdx.x & 63, wv = threadIdx.x >> 6;
    float acc[16];
    float b = bn[lane];
#pragma unroll
    for (int nn = 0; nn < 16; ++nn) acc[nn] = b;
#pragma unroll 1
    for (int k0 = 0; k0 < 32; k0 += 4) {
        float w0 = Wn[(k0 + 0) * 64 + lane];
        float w1 = Wn[(k0 + 1) * 64 + lane];
        float w2 = Wn[(k0 + 2) * 64 + lane];
        float w3 = Wn[(k0 + 3) * 64 + lane];
#pragma unroll
        for (int nn = 0; nn < 16; ++nn) {
            int row = wv * 16 + nn;
            float4 hv = *(const float4*)&sx[row * 32 + k0];
            acc[nn] = fmaf(hv.x, w0, fmaf(hv.y, w1, fmaf(hv.z, w2, fmaf(hv.w, w3, acc[nn]))));
        }
    }
#pragma unroll
    for (int nn = 0; nn < 16; ++nn) {
        int n = base + wv * 16 + nn;
        if (n < Nn) h[(size_t)n * 64 + lane] = fmaxf(acc[nn], 0.f);
    }
}

// Wqm[j][l'=(h,i)] = sum_c Wq[j][h*16+c] * We[i][h*16+c];  bqm likewise from bq
__global__ void k_wqm(const float* __restrict__ Wq, const float* __restrict__ bq,
                      const float* __restrict__ We, float* __restrict__ Wqm,
                      float* __restrict__ bqm) {
    for (int o = threadIdx.x; o < 64 * 64; o += 256) {
        int j = o >> 6, lp = o & 63, hh = lp >> 4, ii = lp & 15;
        float acc = 0.f;
#pragma unroll
        for (int c = 0; c < 16; ++c)
            acc += Wq[j * 64 + hh * 16 + c] * We[ii * 64 + hh * 16 + c];
        Wqm[o] = acc;
    }
    if (threadIdx.x < 64) {
        int hh = threadIdx.x >> 4, ii = threadIdx.x & 15;
        float acc = 0.f;
#pragma unroll
        for (int c = 0; c < 16; ++c)
            acc += bq[hh * 16 + c] * We[ii * 64 + hh * 16 + c];
        bqm[threadIdx.x] = acc;
    }
}

// qn,kn,vn,tq,sn = h@{Wq,Wk,Wv,Wqm,Ws}+bias. Register-blocked 5-in-1 GEMM.
// k0 loop sequential (unroll 1) -> live set ~130 VGPRs, no spill.
__global__ __launch_bounds__(256) void k_qkvt(const float* __restrict__ h,
                       const float* __restrict__ Wq, const float* __restrict__ bq,
                       const float* __restrict__ Wk, const float* __restrict__ bk,
                       const float* __restrict__ Wv, const float* __restrict__ bv,
                       const float* __restrict__ Wqm, const float* __restrict__ bqm,
                       const float* __restrict__ Ws, const float* __restrict__ bs,
                       float* __restrict__ qn, float* __restrict__ kn,
                       float* __restrict__ vn, float* __restrict__ tq,
                       float* __restrict__ sn) {
    __shared__ float sh[64 * 64];
    int base = blockIdx.x * 64;
    for (int i = threadIdx.x; i < 1024; i += 256) {       // 64 rows x 64 cols, float4
        int off = i * 4, row = off >> 6;
        float4 v = (base + row < Nn) ? ((const float4*)(h))[((size_t)base * 64 + off) >> 2]
                                     : make_float4(0.f, 0.f, 0.f, 0.f);
        ((float4*)sh)[i] = v;
    }
    __syncthreads();
    int lane = threadIdx.x & 63, wv = threadIdx.x >> 6;
    float aq[16], ak[16], av[16], at[16], as_[16];
    float _bq = bq[lane], _bk = bk[lane], _bv = bv[lane], _bt = bqm[lane], _bs = bs[lane];
#pragma unroll
    for (int nn = 0; nn < 16; ++nn) {
        aq[nn] = _bq; ak[nn] = _bk; av[nn] = _bv; at[nn] = _bt; as_[nn] = _bs;
    }
#pragma unroll 1
    for (int k0 = 0; k0 < 64; k0 += 4) {
        float wq[4], wk[4], wvv[4], wt[4], ws[4];
#pragma unroll
        for (int j = 0; j < 4; ++j) {
            wq[j] = Wq[(k0 + j) * 64 + lane];
            wk[j] = Wk[(k0 + j) * 64 + lane];
            wvv[j] = Wv[(k0 + j) * 64 + lane];
            wt[j] = Wqm[(k0 + j) * 64 + lane];
            ws[j] = Ws[(k0 + j) * 64 + lane];
        }
#pragma unroll
        for (int nn = 0; nn < 16; ++nn) {
            int row = wv * 16 + nn;
            float4 hv = *(const float4*)&sh[row * 64 + k0];
            aq[nn] = fmaf(hv.x, wq[0], fmaf(hv.y, wq[1], fmaf(hv.z, wq[2], fmaf(hv.w, wq[3], aq[nn]))));
            ak[nn] = fmaf(hv.x, wk[0], fmaf(hv.y, wk[1], fmaf(hv.z, wk[2], fmaf(hv.w, wk[3], ak[nn]))));
            av[nn] = fmaf(hv.x, wvv[0], fmaf(hv.y, wvv[1], fmaf(hv.z, wvv[2], fmaf(hv.w, wvv[3], av[nn]))));
            at[nn] = fmaf(hv.x, wt[0], fmaf(hv.y, wt[1], fmaf(hv.z, wt[2], fmaf(hv.w, wt[3], at[nn]))));
            as_[nn] = fmaf(hv.x, ws[0], fmaf(hv.y, ws[1], fmaf(hv.z, ws[2], fmaf(hv.w, ws[3], as_[nn]))));
        }
    }
#pragma unroll
    for (int nn = 0; nn < 16; ++nn) {
        int n = base + wv * 16 + nn;
        if (n < Nn) {
            size_t o = (size_t)n * 64 + lane;
            qn[o] = aq[nn]; kn[o] = ak[nn]; vn[o] = av[nn]; tq[o] = at[nn]; sn[o] = as_[nn];
        }
    }
}

// Fully-fused per-layer edge pass: one wave per dst node, online softmax,
// 4-edge unroll for ILP. alpha' = (q.k + ea.tq) * 0.25*log2(e); softmax in
// base-2 (identical weights: 2^((a-m)log2e) == exp(a-m), denom identical).
// Per edge: kn/vn row gathers (L2), ea 64B gather, 4-deep shfl reduce x4
// independent chains. No alpha array, ea read ONCE per layer.
// exp2 via __builtin_exp2f (NOT __exp2f: glibc math.h owns that name).
__global__ __launch_bounds__(256) void k_layer(float* __restrict__ h,
                      const float* __restrict__ qn, const float* __restrict__ kn,
                      const float* __restrict__ vn, const float* __restrict__ tq,
                      const float* __restrict__ sn, const int* __restrict__ row_ptr,
                      const int* __restrict__ src_perm, const int* __restrict__ eperm,
                      const float* __restrict__ ea, const float* __restrict__ We) {
    __shared__ float sWe[1024];
    __shared__ float tile[4][64];
    for (int t = threadIdx.x; t < 1024; t += 256) sWe[t] = We[t];
    __syncthreads();
    int lane = threadIdx.x & 63, wv = threadIdx.x >> 6;
    int hh = lane >> 4, cc = lane & 15;
    int n = blockIdx.x * 4 + wv;
    if (n >= Nn) return;
    int beg = row_ptr[n], end = row_ptr[n + 1];
    const float SC = 0.25f * 1.4426950408889634f;  // 1/sqrt(C) * log2(e)
    float q = qn[(size_t)n * 64 + lane];
    float t = tq[(size_t)n * 64 + lane];
    float m = -INFINITY, accd = 0.f, accv = 0.f, acce = 0.f;
    int idx = beg;
    for (; idx + 4 <= end; idx += 4) {
        int s0 = src_perm[idx], s1 = src_perm[idx + 1];
        int s2 = src_perm[idx + 2], s3 = src_perm[idx + 3];
        int e0 = eperm[idx], e1 = eperm[idx + 1];
        int e2 = eperm[idx + 2], e3 = eperm[idx + 3];
        float k0 = kn[(size_t)s0 * 64 + lane], k1 = kn[(size_t)s1 * 64 + lane];
        float k2 = kn[(size_t)s2 * 64 + lane], k3 = kn[(size_t)s3 * 64 + lane];
        float v0 = vn[(size_t)s0 * 64 + lane], v1 = vn[(size_t)s1 * 64 + lane];
        float v2 = vn[(size_t)s2 * 64 + lane], v3 = vn[(size_t)s3 * 64 + lane];
        float x0 = ea[(size_t)e0 * 16 + cc], x1 = ea[(size_t)e1 * 16 + cc];
        float x2 = ea[(size_t)e2 * 16 + cc], x3 = ea[(size_t)e3 * 16 + cc];
        float a0 = fmaf(q, k0, x0 * t), a1 = fmaf(q, k1, x1 * t);
        float a2 = fmaf(q, k2, x2 * t), a3 = fmaf(q, k3, x3 * t);
        // 4 independent butterfly chains (scheduler interleaves)
        a0 += __shfl_xor(a0, 1, 16); a1 += __shfl_xor(a1, 1, 16);
        a2 += __shfl_xor(a2, 1, 16); a3 += __shfl_xor(a3, 1, 16);
        a0 += __shfl_xor(a0, 2, 16); a1 += __shfl_xor(a1, 2, 16);
        a2 += __shfl_xor(a2, 2, 16); a3 += __shfl_xor(a3, 2, 16);
        a0 += __shfl_xor(a0, 4, 16); a1 += __shfl_xor(a1, 4, 16);
        a2 += __shfl_xor(a2, 4, 16); a3 += __shfl_xor(a3, 4, 16);
        a0 += __shfl_xor(a0, 8, 16); a1 += __shfl_xor(a1, 8, 16);
        a2 += __shfl_xor(a2, 8, 16); a3 += __shfl_xor(a3, 8, 16);
        a0 *= SC; a1 *= SC; a2 *= SC; a3 *= SC;
        float mx = fmaxf(fmaxf(a0, a1), fmaxf(a2, a3));
        float nm = fmaxf(m, mx);
        float w = __builtin_exp2f(m - nm);
        float p0 = __builtin_exp2f(a0 - nm), p1 = __builtin_exp2f(a1 - nm);
        float p2 = __builtin_exp2f(a2 - nm), p3 = __builtin_exp2f(a3 - nm);
        accd = fmaf(accd, w, (p0 + p1) + (p2 + p3));
        accv = fmaf(accv, w, fmaf(p0, v0, fmaf(p1, v1, fmaf(p2, v2, p3 * v3))));
        acce = fmaf(acce, w, fmaf(p0, x0, fmaf(p1, x1, fmaf(p2, x2, p3 * x3))));
        m = nm;
    }
    for (; idx < end; ++idx) {
        int s0 = src_perm[idx], e0 = eperm[idx];
        float k0 = kn[(size_t)s0 * 64 + lane];
        float v0 = vn[(size_t)s0 * 64 + lane];
        float x0 = ea[(size_t)e0 * 16 + cc];
        float a0 = fmaf(q, k0, x0 * t);
        a0 += __shfl_xor(a0, 1, 16);
        a0 += __shfl_xor(a0, 2, 16);
        a0 += __shfl_xor(a0, 4, 16);
        a0 += __shfl_xor(a0, 8, 16);
        a0 *= SC;
        float nm = fmaxf(m, a0);
        float w = __builtin_exp2f(m - nm);
        float p0 = __builtin_exp2f(a0 - nm);
        accd = fmaf(accd, w, p0);
        accv = fmaf(accv, w, p0 * v0);
        acce = fmaf(acce, w, p0 * x0);
        m = nm;
    }
    float inv = 1.f / (accd + 1e-16f);
    tile[wv][lane] = acce * inv;  // wave-local LDS round-trip (lockstep, no barrier)
    float re = 0.f;
#pragma unroll
    for (int i = 0; i < 16; ++i)
        re = fmaf(tile[wv][hh * 16 + i], sWe[i * 64 + lane], re);
    size_t o = (size_t)n * 64 + lane;
    float hv = h[o];
    h[o] = hv + fmaxf(fmaf(accv, inv, re + sn[o]), 0.f);
}

// mean-pool per group (batch sorted -> boundaries) + fused MLP head
__global__ void k_pool(const float* __restrict__ h, const int* __restrict__ gstart,
                       const float* __restrict__ W1, const float* __restrict__ b1,
                       const float* __restrict__ W2, const float* __restrict__ b2,
                       float* __restrict__ out) {
    int g = blockIdx.x;
    int lane = threadIdx.x & 63, wv = threadIdx.x >> 6;
    int beg = gstart[g], end = gstart[g + 1];
    __shared__ float red[4][64];
    __shared__ float sp[64];
    __shared__ float sh[32];
    float acc = 0.f;
    for (int n = beg + wv; n < end; n += 4) acc += h[(size_t)n * 64 + lane];
    red[wv][lane] = acc;
    __syncthreads();
    if (threadIdx.x < 64) {
        float c = fmaxf((float)(end - beg), 1.f);
        sp[lane] = (red[0][lane] + red[1][lane] + red[2][lane] + red[3][lane]) / c;
    }
    __syncthreads();
    if (threadIdx.x < 32) {
        int t = threadIdx.x;
        float a = b1[t];
#pragma unroll
        for (int i = 0; i < 64; ++i) a = fmaf(sp[i], W1[i * 32 + t], a);
        sh[t] = fmaxf(a, 0.f) * W2[t];
    }
    __syncthreads();
    if (threadIdx.x == 0) {
        float s = b2[0];
#pragma unroll
        for (int i = 0; i < 32; ++i) s += sh[i];
        out[g] = s;
    }
}

extern "C" void kernel_launch(void* const* d_in, const int* in_sizes, int n_in,
                              void* d_out, int out_size, void* d_ws, size_t ws_size,
                              hipStream_t stream) {
    const float* x   = (const float*)d_in[0];
    const int*   ei  = (const int*)d_in[1];
    const float* ea  = (const float*)d_in[2];
    const int*   bat = (const int*)d_in[3];
    const float* Wn  = (const float*)d_in[4];
    const float* bn  = (const float*)d_in[5];
    const float* Wq  = (const float*)d_in[6];
    const float* bq  = (const float*)d_in[7];
    const float* Wk  = (const float*)d_in[8];
    const float* bk  = (const float*)d_in[9];
    const float* Wv  = (const float*)d_in[10];
    const float* bv  = (const float*)d_in[11];
    const float* We  = (const float*)d_in[12];
    const float* Wsk = (const float*)d_in[13];
    const float* bs  = (const float*)d_in[14];
    const float* W1  = (const float*)d_in[15];
    const float* b1  = (const float*)d_in[16];
    const float* W2  = (const float*)d_in[17];
    const float* b2  = (const float*)d_in[18];
    float* out = (float*)d_out;

    const size_t NH = (size_t)Nn * 64;
    float* h    = (float*)d_ws;
    float* qn   = h + NH;
    float* kn   = h + 2 * NH;
    float* vn   = h + 3 * NH;
    float* tq   = h + 4 * NH;
    float* sn   = h + 5 * NH;
    float* Wqm  = h + 6 * NH;                  // 4096
    float* bqm  = Wqm + 4096;                  // 64
    int* deg       = (int*)(bqm + 64);         // N
    int* row_ptr   = deg + Nn;                 // N+1
    int* cursor    = row_ptr + Nn + 1;         // N
    int* src_perm  = cursor + Nn;              // E
    int* eperm     = src_perm + Ee;            // E
    int* bsum      = eperm + Ee;               // 256
    int* gstart    = bsum + 256;               // G+1

    const int NB = 196;  // ceil(50000/256)
    hipMemsetAsync(deg, 0, Nn * sizeof(int), stream);
    k_hist<<<(Ee + 255) / 256, 256, 0, stream>>>(ei, deg);
    k_scan1<<<NB, 256, 0, stream>>>(deg, row_ptr, bsum);
    k_scan2<<<1, 256, 0, stream>>>(bsum, NB);
    k_scan3<<<(Nn + 256) / 256, 256, 0, stream>>>(row_ptr, bsum);
    hipMemcpyAsync(cursor, row_ptr, Nn * sizeof(int), hipMemcpyDeviceToDevice, stream);
    k_scatter<<<(Ee + 255) / 256, 256, 0, stream>>>(ei, cursor, src_perm, eperm);
    k_gbound<<<(Nn + 255) / 256, 256, 0, stream>>>(bat, gstart);

    int nodeBlocks = (Nn + 63) / 64;
    k_encode<<<nodeBlocks, 256, 0, stream>>>(x, Wn, bn, h);
    for (int l = 0; l < 3; ++l) {
        k_wqm<<<1, 256, 0, stream>>>(Wq + l * 4096, bq + l * 64, We + l * 1024, Wqm, bqm);
        k_qkvt<<<nodeBlocks, 256, 0, stream>>>(h, Wq + l * 4096, bq + l * 64,
                                               Wk + l * 4096, bk + l * 64,
                                               Wv + l * 4096, bv + l * 64,
                                               Wqm, bqm, Wsk + l * 4096, bs + l * 64,
                                               qn, kn, vn, tq, sn);
        k_layer<<<(Nn + 3) / 4, 256, 0, stream>>>(h, qn, kn, vn, tq, sn, row_ptr,
                                                  src_perm, eperm, ea, We + l * 1024);
    }
    k_pool<<<Gg, 256, 0, stream>>>(h, gstart, W1, b1, W2, b2, out);
}

// Round 9
// 1010.064 us; speedup vs baseline: 6.9133x; 1.0078x over previous
//
#include <hip/hip_runtime.h>

#define Nn 50000
#define Ee 1600000
#define Gg 64

// ---------------- one-time CSR build ----------------
__global__ void k_hist(const int* __restrict__ ei, int* __restrict__ deg) {
    int e = blockIdx.x * blockDim.x + threadIdx.x;
    if (e < Ee) atomicAdd(&deg[ei[Ee + e]], 1);
}

__global__ void k_scan1(const int* __restrict__ deg, int* __restrict__ row_ptr,
                        int* __restrict__ bsum) {
    __shared__ int buf[256];
    int i = blockIdx.x * 256 + threadIdx.x;
    int v = (i < Nn) ? deg[i] : 0;
    buf[threadIdx.x] = v;
    __syncthreads();
    for (int off = 1; off < 256; off <<= 1) {
        int t = (threadIdx.x >= off) ? buf[threadIdx.x - off] : 0;
        __syncthreads();
        buf[threadIdx.x] += t;
        __syncthreads();
    }
    if (i < Nn) row_ptr[i + 1] = buf[threadIdx.x];  // block-local inclusive
    if (threadIdx.x == 255) bsum[blockIdx.x] = buf[255];
}

__global__ void k_scan2(int* __restrict__ bsum, int nb) {
    __shared__ int buf[256];
    int v = (threadIdx.x < nb) ? bsum[threadIdx.x] : 0;
    buf[threadIdx.x] = v;
    __syncthreads();
    for (int off = 1; off < 256; off <<= 1) {
        int t = (threadIdx.x >= off) ? buf[threadIdx.x - off] : 0;
        __syncthreads();
        buf[threadIdx.x] += t;
        __syncthreads();
    }
    if (threadIdx.x < nb) bsum[threadIdx.x] = buf[threadIdx.x];  // inclusive
}

__global__ void k_scan3(int* __restrict__ row_ptr, const int* __restrict__ bsum) {
    int i = blockIdx.x * 256 + threadIdx.x;  // i in [0, Nn]
    if (i > Nn) return;
    if (i == 0) { row_ptr[0] = 0; return; }
    int b = (i - 1) >> 8;
    if (b > 0) row_ptr[i] += bsum[b - 1];
}

__global__ void k_scatter(const int* __restrict__ ei, int* __restrict__ cursor,
                          int* __restrict__ src_perm, int* __restrict__ eperm) {
    int e = blockIdx.x * blockDim.x + threadIdx.x;
    if (e >= Ee) return;
    int dst = ei[Ee + e];
    int pos = atomicAdd(&cursor[dst], 1);
    src_perm[pos] = ei[e];
    eperm[pos] = e;
}

// one-time: permute ea rows into CSR edge order (random 64B read, coalesced write)
__global__ void k_easort(const float* __restrict__ ea, const int* __restrict__ eperm,
                         float* __restrict__ ea_s) {
    long t = (long)blockIdx.x * blockDim.x + threadIdx.x;  // E*4 float4 slots
    if (t >= (long)Ee * 4) return;
    long idx = t >> 2;
    int e = eperm[idx];
    ((float4*)ea_s)[t] = ((const float4*)ea)[(long)e * 4 + (t & 3)];
}

__global__ void k_gbound(const int* __restrict__ batch, int* __restrict__ gstart) {
    int n = blockIdx.x * blockDim.x + threadIdx.x;
    if (n >= Nn) return;
    int b = batch[n];
    if (n == 0) { for (int g = 0; g <= b; ++g) gstart[g] = 0; }
    else { int bp = batch[n - 1]; for (int g = bp + 1; g <= b; ++g) gstart[g] = n; }
    if (n == Nn - 1) { for (int g = b + 1; g <= Gg; ++g) gstart[g] = Nn; }
}

// ---------------- node kernels ----------------
// h = relu(x @ Wn + bn). Register-blocked: x-tile in LDS, Wn chunk in regs.
// k0 loop NOT unrolled (full unroll -> load hoisting -> spill, see R4/R5).
__global__ __launch_bounds__(256) void k_encode(const float* __restrict__ x,
                         const float* __restrict__ Wn,
                         const float* __restrict__ bn, float* __restrict__ h) {
    __shared__ float sx[64 * 32];
    int base = blockIdx.x * 64;
    for (int i = threadIdx.x; i < 512; i += 256) {        // 64 rows x 32 cols, float4
        int off = i * 4, row = off >> 5;
        float4 v = (base + row < Nn) ? ((const float4*)(x))[(base * 32 + off) >> 2]
                                     : make_float4(0.f, 0.f, 0.f, 0.f);
        ((float4*)sx)[i] = v;
    }
    __syncthreads();
    int lane = threadIdx.x & 63, wv = threadIdx.x >> 6;
    float acc[16];
    float b = bn[lane];
#pragma unroll
    for (int nn = 0; nn < 16; ++nn) acc[nn] = b;
#pragma unroll 1
    for (int k0 = 0; k0 < 32; k0 += 4) {
        float w0 = Wn[(k0 + 0) * 64 + lane];
        float w1 = Wn[(k0 + 1) * 64 + lane];
        float w2 = Wn[(k0 + 2) * 64 + lane];
        float w3 = Wn[(k0 + 3) * 64 + lane];
#pragma unroll
        for (int nn = 0; nn < 16; ++nn) {
            int row = wv * 16 + nn;
            float4 hv = *(const float4*)&sx[row * 32 + k0];
            acc[nn] = fmaf(hv.x, w0, fmaf(hv.y, w1, fmaf(hv.z, w2, fmaf(hv.w, w3, acc[nn]))));
        }
    }
#pragma unroll
    for (int nn = 0; nn < 16; ++nn) {
        int n = base + wv * 16 + nn;
        if (n < Nn) h[(size_t)n * 64 + lane] = fmaxf(acc[nn], 0.f);
    }
}

// All 3 layers' Wqm/bqm in one launch (block = layer).
// Wqm[j][l'=(h,i)] = sum_c Wq[j][h*16+c] * We[i][h*16+c];  bqm likewise from bq
__global__ void k_wqm3(const float* __restrict__ Wq_all, const float* __restrict__ bq_all,
                       const float* __restrict__ We_all, float* __restrict__ Wqm3,
                       float* __restrict__ bqm3) {
    int l = blockIdx.x;
    const float* Wq = Wq_all + l * 4096;
    const float* bq = bq_all + l * 64;
    const float* We = We_all + l * 1024;
    float* Wqm = Wqm3 + l * 4096;
    float* bqm = bqm3 + l * 64;
    for (int o = threadIdx.x; o < 64 * 64; o += 256) {
        int j = o >> 6, lp = o & 63, hh = lp >> 4, ii = lp & 15;
        float acc = 0.f;
#pragma unroll
        for (int c = 0; c < 16; ++c)
            acc += Wq[j * 64 + hh * 16 + c] * We[ii * 64 + hh * 16 + c];
        Wqm[o] = acc;
    }
    if (threadIdx.x < 64) {
        int hh = threadIdx.x >> 4, ii = threadIdx.x & 15;
        float acc = 0.f;
#pragma unroll
        for (int c = 0; c < 16; ++c)
            acc += bq[hh * 16 + c] * We[ii * 64 + hh * 16 + c];
        bqm[threadIdx.x] = acc;
    }
}

// qn,kn,vn,tq,sn = h@{Wq,Wk,Wv,Wqm,Ws}+bias. Register-blocked 5-in-1 GEMM.
// k0 loop sequential (unroll 1) -> live set ~130 VGPRs, no spill.
__global__ __launch_bounds__(256) void k_qkvt(const float* __restrict__ h,
                       const float* __restrict__ Wq, const float* __restrict__ bq,
                       const float* __restrict__ Wk, const float* __restrict__ bk,
                       const float* __restrict__ Wv, const float* __restrict__ bv,
                       const float* __restrict__ Wqm, const float* __restrict__ bqm,
                       const float* __restrict__ Ws, const float* __restrict__ bs,
                       float* __restrict__ qn, float* __restrict__ kn,
                       float* __restrict__ vn, float* __restrict__ tq,
                       float* __restrict__ sn) {
    __shared__ float sh[64 * 64];
    int base = blockIdx.x * 64;
    for (int i = threadIdx.x; i < 1024; i += 256) {       // 64 rows x 64 cols, float4
        int off = i * 4, row = off >> 6;
        float4 v = (base + row < Nn) ? ((const float4*)(h))[((size_t)base * 64 + off) >> 2]
                                     : make_float4(0.f, 0.f, 0.f, 0.f);
        ((float4*)sh)[i] = v;
    }
    __syncthreads();
    int lane = threadIdx.x & 63, wv = threadIdx.x >> 6;
    float aq[16], ak[16], av[16], at[16], as_[16];
    float _bq = bq[lane], _bk = bk[lane], _bv = bv[lane], _bt = bqm[lane], _bs = bs[lane];
#pragma unroll
    for (int nn = 0; nn < 16; ++nn) {
        aq[nn] = _bq; ak[nn] = _bk; av[nn] = _bv; at[nn] = _bt; as_[nn] = _bs;
    }
#pragma unroll 1
    for (int k0 = 0; k0 < 64; k0 += 4) {
        float wq[4], wk[4], wvv[4], wt[4], ws[4];
#pragma unroll
        for (int j = 0; j < 4; ++j) {
            wq[j] = Wq[(k0 + j) * 64 + lane];
            wk[j] = Wk[(k0 + j) * 64 + lane];
            wvv[j] = Wv[(k0 + j) * 64 + lane];
            wt[j] = Wqm[(k0 + j) * 64 + lane];
            ws[j] = Ws[(k0 + j) * 64 + lane];
        }
#pragma unroll
        for (int nn = 0; nn < 16; ++nn) {
            int row = wv * 16 + nn;
            float4 hv = *(const float4*)&sh[row * 64 + k0];
            aq[nn] = fmaf(hv.x, wq[0], fmaf(hv.y, wq[1], fmaf(hv.z, wq[2], fmaf(hv.w, wq[3], aq[nn]))));
            ak[nn] = fmaf(hv.x, wk[0], fmaf(hv.y, wk[1], fmaf(hv.z, wk[2], fmaf(hv.w, wk[3], ak[nn]))));
            av[nn] = fmaf(hv.x, wvv[0], fmaf(hv.y, wvv[1], fmaf(hv.z, wvv[2], fmaf(hv.w, wvv[3], av[nn]))));
            at[nn] = fmaf(hv.x, wt[0], fmaf(hv.y, wt[1], fmaf(hv.z, wt[2], fmaf(hv.w, wt[3], at[nn]))));
            as_[nn] = fmaf(hv.x, ws[0], fmaf(hv.y, ws[1], fmaf(hv.z, ws[2], fmaf(hv.w, ws[3], as_[nn]))));
        }
    }
#pragma unroll
    for (int nn = 0; nn < 16; ++nn) {
        int n = base + wv * 16 + nn;
        if (n < Nn) {
            size_t o = (size_t)n * 64 + lane;
            qn[o] = aq[nn]; kn[o] = ak[nn]; vn[o] = av[nn]; tq[o] = at[nn]; sn[o] = as_[nn];
        }
    }
}

// Fully-fused per-layer edge pass: one wave per dst node, online softmax in
// base-2, 4-edge unroll for ILP. SORTED: ea pre-permuted to CSR order ->
// sequential streaming, no eperm indirection (R8: random 64B ea gather was
// ~40% of the 488 MB FETCH).
template <bool SORTED>
__global__ __launch_bounds__(256) void k_layer(float* __restrict__ h,
                      const float* __restrict__ qn, const float* __restrict__ kn,
                      const float* __restrict__ vn, const float* __restrict__ tq,
                      const float* __restrict__ sn, const int* __restrict__ row_ptr,
                      const int* __restrict__ src_perm, const int* __restrict__ eperm,
                      const float* __restrict__ ea, const float* __restrict__ We) {
    __shared__ float sWe[1024];
    __shared__ float tile[4][64];
    for (int t = threadIdx.x; t < 1024; t += 256) sWe[t] = We[t];
    __syncthreads();
    int lane = threadIdx.x & 63, wv = threadIdx.x >> 6;
    int hh = lane >> 4, cc = lane & 15;
    int n = blockIdx.x * 4 + wv;
    if (n >= Nn) return;
    int beg = row_ptr[n], end = row_ptr[n + 1];
    const float SC = 0.25f * 1.4426950408889634f;  // 1/sqrt(C) * log2(e)
    float q = qn[(size_t)n * 64 + lane];
    float t = tq[(size_t)n * 64 + lane];
    float m = -INFINITY, accd = 0.f, accv = 0.f, acce = 0.f;
    int idx = beg;
    for (; idx + 4 <= end; idx += 4) {
        int s0 = src_perm[idx], s1 = src_perm[idx + 1];
        int s2 = src_perm[idx + 2], s3 = src_perm[idx + 3];
        long o0, o1, o2, o3;
        if (SORTED) {
            o0 = (long)idx * 16; o1 = o0 + 16; o2 = o0 + 32; o3 = o0 + 48;
        } else {
            o0 = (long)eperm[idx] * 16;     o1 = (long)eperm[idx + 1] * 16;
            o2 = (long)eperm[idx + 2] * 16; o3 = (long)eperm[idx + 3] * 16;
        }
        float k0 = kn[(size_t)s0 * 64 + lane], k1 = kn[(size_t)s1 * 64 + lane];
        float k2 = kn[(size_t)s2 * 64 + lane], k3 = kn[(size_t)s3 * 64 + lane];
        float v0 = vn[(size_t)s0 * 64 + lane], v1 = vn[(size_t)s1 * 64 + lane];
        float v2 = vn[(size_t)s2 * 64 + lane], v3 = vn[(size_t)s3 * 64 + lane];
        float x0 = ea[o0 + cc], x1 = ea[o1 + cc];
        float x2 = ea[o2 + cc], x3 = ea[o3 + cc];
        float a0 = fmaf(q, k0, x0 * t), a1 = fmaf(q, k1, x1 * t);
        float a2 = fmaf(q, k2, x2 * t), a3 = fmaf(q, k3, x3 * t);
        // 4 independent butterfly chains (scheduler interleaves)
        a0 += __shfl_xor(a0, 1, 16); a1 += __shfl_xor(a1, 1, 16);
        a2 += __shfl_xor(a2, 1, 16); a3 += __shfl_xor(a3, 1, 16);
        a0 += __shfl_xor(a0, 2, 16); a1 += __shfl_xor(a1, 2, 16);
        a2 += __shfl_xor(a2, 2, 16); a3 += __shfl_xor(a3, 2, 16);
        a0 += __shfl_xor(a0, 4, 16); a1 += __shfl_xor(a1, 4, 16);
        a2 += __shfl_xor(a2, 4, 16); a3 += __shfl_xor(a3, 4, 16);
        a0 += __shfl_xor(a0, 8, 16); a1 += __shfl_xor(a1, 8, 16);
        a2 += __shfl_xor(a2, 8, 16); a3 += __shfl_xor(a3, 8, 16);
        a0 *= SC; a1 *= SC; a2 *= SC; a3 *= SC;
        float mx = fmaxf(fmaxf(a0, a1), fmaxf(a2, a3));
        float nm = fmaxf(m, mx);
        float w = __builtin_exp2f(m - nm);
        float p0 = __builtin_exp2f(a0 - nm), p1 = __builtin_exp2f(a1 - nm);
        float p2 = __builtin_exp2f(a2 - nm), p3 = __builtin_exp2f(a3 - nm);
        accd = fmaf(accd, w, (p0 + p1) + (p2 + p3));
        accv = fmaf(accv, w, fmaf(p0, v0, fmaf(p1, v1, fmaf(p2, v2, p3 * v3))));
        acce = fmaf(acce, w, fmaf(p0, x0, fmaf(p1, x1, fmaf(p2, x2, p3 * x3))));
        m = nm;
    }
    for (; idx < end; ++idx) {
        int s0 = src_perm[idx];
        long o0 = SORTED ? (long)idx * 16 : (long)eperm[idx] * 16;
        float k0 = kn[(size_t)s0 * 64 + lane];
        float v0 = vn[(size_t)s0 * 64 + lane];
        float x0 = ea[o0 + cc];
        float a0 = fmaf(q, k0, x0 * t);
        a0 += __shfl_xor(a0, 1, 16);
        a0 += __shfl_xor(a0, 2, 16);
        a0 += __shfl_xor(a0, 4, 16);
        a0 += __shfl_xor(a0, 8, 16);
        a0 *= SC;
        float nm = fmaxf(m, a0);
        float w = __builtin_exp2f(m - nm);
        float p0 = __builtin_exp2f(a0 - nm);
        accd = fmaf(accd, w, p0);
        accv = fmaf(accv, w, p0 * v0);
        acce = fmaf(acce, w, p0 * x0);
        m = nm;
    }
    float inv = 1.f / (accd + 1e-16f);
    tile[wv][lane] = acce * inv;  // wave-local LDS round-trip (lockstep, no barrier)
    float re = 0.f;
#pragma unroll
    for (int i = 0; i < 16; ++i)
        re = fmaf(tile[wv][hh * 16 + i], sWe[i * 64 + lane], re);
    size_t o = (size_t)n * 64 + lane;
    float hv = h[o];
    h[o] = hv + fmaxf(fmaf(accv, inv, re + sn[o]), 0.f);
}

// mean-pool per group (batch sorted -> boundaries) + fused MLP head
__global__ void k_pool(const float* __restrict__ h, const int* __restrict__ gstart,
                       const float* __restrict__ W1, const float* __restrict__ b1,
                       const float* __restrict__ W2, const float* __restrict__ b2,
                       float* __restrict__ out) {
    int g = blockIdx.x;
    int lane = threadIdx.x & 63, wv = threadIdx.x >> 6;
    int beg = gstart[g], end = gstart[g + 1];
    __shared__ float red[4][64];
    __shared__ float sp[64];
    __shared__ float sh[32];
    float acc = 0.f;
    for (int n = beg + wv; n < end; n += 4) acc += h[(size_t)n * 64 + lane];
    red[wv][lane] = acc;
    __syncthreads();
    if (threadIdx.x < 64) {
        float c = fmaxf((float)(end - beg), 1.f);
        sp[lane] = (red[0][lane] + red[1][lane] + red[2][lane] + red[3][lane]) / c;
    }
    __syncthreads();
    if (threadIdx.x < 32) {
        int t = threadIdx.x;
        float a = b1[t];
#pragma unroll
        for (int i = 0; i < 64; ++i) a = fmaf(sp[i], W1[i * 32 + t], a);
        sh[t] = fmaxf(a, 0.f) * W2[t];
    }
    __syncthreads();
    if (threadIdx.x == 0) {
        float s = b2[0];
#pragma unroll
        for (int i = 0; i < 32; ++i) s += sh[i];
        out[g] = s;
    }
}

extern "C" void kernel_launch(void* const* d_in, const int* in_sizes, int n_in,
                              void* d_out, int out_size, void* d_ws, size_t ws_size,
                              hipStream_t stream) {
    const float* x   = (const float*)d_in[0];
    const int*   ei  = (const int*)d_in[1];
    const float* ea  = (const float*)d_in[2];
    const int*   bat = (const int*)d_in[3];
    const float* Wn  = (const float*)d_in[4];
    const float* bn  = (const float*)d_in[5];
    const float* Wq  = (const float*)d_in[6];
    const float* bq  = (const float*)d_in[7];
    const float* Wk  = (const float*)d_in[8];
    const float* bk  = (const float*)d_in[9];
    const float* Wv  = (const float*)d_in[10];
    const float* bv  = (const float*)d_in[11];
    const float* We  = (const float*)d_in[12];
    const float* Wsk = (const float*)d_in[13];
    const float* bs  = (const float*)d_in[14];
    const float* W1  = (const float*)d_in[15];
    const float* b1  = (const float*)d_in[16];
    const float* W2  = (const float*)d_in[17];
    const float* b2  = (const float*)d_in[18];
    float* out = (float*)d_out;

    const size_t NH = (size_t)Nn * 64;
    float* h    = (float*)d_ws;
    float* qn   = h + NH;
    float* kn   = h + 2 * NH;
    float* vn   = h + 3 * NH;
    float* tq   = h + 4 * NH;
    float* sn   = h + 5 * NH;
    float* Wqm3 = h + 6 * NH;                  // 3*4096
    float* bqm3 = Wqm3 + 3 * 4096;             // 3*64
    int* deg       = (int*)(bqm3 + 3 * 64);    // N
    int* row_ptr   = deg + Nn;                 // N+1
    int* cursor    = row_ptr + Nn + 1;         // N
    int* src_perm  = cursor + Nn;              // E
    int* eperm     = src_perm + Ee;            // E
    int* bsum      = eperm + Ee;               // 256
    int* gstart    = bsum + 256;               // G+1
    float* ea_sorted = (float*)(gstart + Gg + 1);  // E*16 (optional)
    size_t need_sorted = ((char*)(ea_sorted + (size_t)Ee * 16)) - (char*)d_ws;
    bool sorted = ws_size >= need_sorted;      // constant across calls

    const int NB = 196;  // ceil(50000/256)
    hipMemsetAsync(deg, 0, Nn * sizeof(int), stream);
    k_hist<<<(Ee + 255) / 256, 256, 0, stream>>>(ei, deg);
    k_scan1<<<NB, 256, 0, stream>>>(deg, row_ptr, bsum);
    k_scan2<<<1, 256, 0, stream>>>(bsum, NB);
    k_scan3<<<(Nn + 256) / 256, 256, 0, stream>>>(row_ptr, bsum);
    hipMemcpyAsync(cursor, row_ptr, Nn * sizeof(int), hipMemcpyDeviceToDevice, stream);
    k_scatter<<<(Ee + 255) / 256, 256, 0, stream>>>(ei, cursor, src_perm, eperm);
    if (sorted)
        k_easort<<<(Ee * 4 + 255) / 256, 256, 0, stream>>>(ea, eperm, ea_sorted);
    k_gbound<<<(Nn + 255) / 256, 256, 0, stream>>>(bat, gstart);
    k_wqm3<<<3, 256, 0, stream>>>(Wq, bq, We, Wqm3, bqm3);

    int nodeBlocks = (Nn + 63) / 64;
    k_encode<<<nodeBlocks, 256, 0, stream>>>(x, Wn, bn, h);
    for (int l = 0; l < 3; ++l) {
        k_qkvt<<<nodeBlocks, 256, 0, stream>>>(h, Wq + l * 4096, bq + l * 64,
                                               Wk + l * 4096, bk + l * 64,
                                               Wv + l * 4096, bv + l * 64,
                                               Wqm3 + l * 4096, bqm3 + l * 64,
                                               Wsk + l * 4096, bs + l * 64,
                                               qn, kn, vn, tq, sn);
        if (sorted)
            k_layer<true><<<(Nn + 3) / 4, 256, 0, stream>>>(h, qn, kn, vn, tq, sn,
                    row_ptr, src_perm, eperm, ea_sorted, We + l * 1024);
        else
            k_layer<false><<<(Nn + 3) / 4, 256, 0, stream>>>(h, qn, kn, vn, tq, sn,
                    row_ptr, src_perm, eperm, ea, We + l * 1024);
    }
    k_pool<<<Gg, 256, 0, stream>>>(h, gstart, W1, b1, W2, b2, out);
}

// Round 10
// 903.016 us; speedup vs baseline: 7.7329x; 1.1185x over previous
//
#include <hip/hip_runtime.h>
#include <hip/hip_fp16.h>

#define Nn 50000
#define Ee 1600000
#define Gg 64

// ---------------- one-time CSR build ----------------
__global__ void k_hist(const int* __restrict__ ei, int* __restrict__ deg) {
    int e = blockIdx.x * blockDim.x + threadIdx.x;
    if (e < Ee) atomicAdd(&deg[ei[Ee + e]], 1);
}

__global__ void k_scan1(const int* __restrict__ deg, int* __restrict__ row_ptr,
                        int* __restrict__ bsum) {
    __shared__ int buf[256];
    int i = blockIdx.x * 256 + threadIdx.x;
    int v = (i < Nn) ? deg[i] : 0;
    buf[threadIdx.x] = v;
    __syncthreads();
    for (int off = 1; off < 256; off <<= 1) {
        int t = (threadIdx.x >= off) ? buf[threadIdx.x - off] : 0;
        __syncthreads();
        buf[threadIdx.x] += t;
        __syncthreads();
    }
    if (i < Nn) row_ptr[i + 1] = buf[threadIdx.x];  // block-local inclusive
    if (threadIdx.x == 255) bsum[blockIdx.x] = buf[255];
}

__global__ void k_scan2(int* __restrict__ bsum, int nb) {
    __shared__ int buf[256];
    int v = (threadIdx.x < nb) ? bsum[threadIdx.x] : 0;
    buf[threadIdx.x] = v;
    __syncthreads();
    for (int off = 1; off < 256; off <<= 1) {
        int t = (threadIdx.x >= off) ? buf[threadIdx.x - off] : 0;
        __syncthreads();
        buf[threadIdx.x] += t;
        __syncthreads();
    }
    if (threadIdx.x < nb) bsum[threadIdx.x] = buf[threadIdx.x];  // inclusive
}

__global__ void k_scan3(int* __restrict__ row_ptr, const int* __restrict__ bsum) {
    int i = blockIdx.x * 256 + threadIdx.x;  // i in [0, Nn]
    if (i > Nn) return;
    if (i == 0) { row_ptr[0] = 0; return; }
    int b = (i - 1) >> 8;
    if (b > 0) row_ptr[i] += bsum[b - 1];
}

__global__ void k_scatter(const int* __restrict__ ei, int* __restrict__ cursor,
                          int* __restrict__ src_perm, int* __restrict__ eperm) {
    int e = blockIdx.x * blockDim.x + threadIdx.x;
    if (e >= Ee) return;
    int dst = ei[Ee + e];
    int pos = atomicAdd(&cursor[dst], 1);
    src_perm[pos] = ei[e];
    eperm[pos] = e;
}

// one-time: permute ea rows into CSR order AND convert to fp16
// (random 64B read, coalesced 32B/row write)
__global__ void k_easort(const float* __restrict__ ea, const int* __restrict__ eperm,
                         __half* __restrict__ ea_h) {
    long t = (long)blockIdx.x * blockDim.x + threadIdx.x;  // E*4 quarter-rows
    if (t >= (long)Ee * 4) return;
    long idx = t >> 2;
    int e = eperm[idx];
    float4 v = ((const float4*)ea)[(long)e * 4 + (t & 3)];
    __half2 lo = __floats2half2_rn(v.x, v.y);
    __half2 hi = __floats2half2_rn(v.z, v.w);
    ((__half2*)ea_h)[t * 2]     = lo;
    ((__half2*)ea_h)[t * 2 + 1] = hi;
}

__global__ void k_gbound(const int* __restrict__ batch, int* __restrict__ gstart) {
    int n = blockIdx.x * blockDim.x + threadIdx.x;
    if (n >= Nn) return;
    int b = batch[n];
    if (n == 0) { for (int g = 0; g <= b; ++g) gstart[g] = 0; }
    else { int bp = batch[n - 1]; for (int g = bp + 1; g <= b; ++g) gstart[g] = n; }
    if (n == Nn - 1) { for (int g = b + 1; g <= Gg; ++g) gstart[g] = Nn; }
}

// ---------------- node kernels ----------------
// h = relu(x @ Wn + bn). Register-blocked: x-tile in LDS, Wn chunk in regs.
// k0 loop NOT unrolled (full unroll -> load hoisting -> spill, see R4/R5).
__global__ __launch_bounds__(256) void k_encode(const float* __restrict__ x,
                         const float* __restrict__ Wn,
                         const float* __restrict__ bn, float* __restrict__ h) {
    __shared__ float sx[64 * 32];
    int base = blockIdx.x * 64;
    for (int i = threadIdx.x; i < 512; i += 256) {        // 64 rows x 32 cols, float4
        int off = i * 4, row = off >> 5;
        float4 v = (base + row < Nn) ? ((const float4*)(x))[(base * 32 + off) >> 2]
                                     : make_float4(0.f, 0.f, 0.f, 0.f);
        ((float4*)sx)[i] = v;
    }
    __syncthreads();
    int lane = threadIdx.x & 63, wv = threadIdx.x >> 6;
    float acc[16];
    float b = bn[lane];
#pragma unroll
    for (int nn = 0; nn < 16; ++nn) acc[nn] = b;
#pragma unroll 1
    for (int k0 = 0; k0 < 32; k0 += 4) {
        float w0 = Wn[(k0 + 0) * 64 + lane];
        float w1 = Wn[(k0 + 1) * 64 + lane];
        float w2 = Wn[(k0 + 2) * 64 + lane];
        float w3 = Wn[(k0 + 3) * 64 + lane];
#pragma unroll
        for (int nn = 0; nn < 16; ++nn) {
            int row = wv * 16 + nn;
            float4 hv = *(const float4*)&sx[row * 32 + k0];
            acc[nn] = fmaf(hv.x, w0, fmaf(hv.y, w1, fmaf(hv.z, w2, fmaf(hv.w, w3, acc[nn]))));
        }
    }
#pragma unroll
    for (int nn = 0; nn < 16; ++nn) {
        int n = base + wv * 16 + nn;
        if (n < Nn) h[(size_t)n * 64 + lane] = fmaxf(acc[nn], 0.f);
    }
}

// All 3 layers' Wqm/bqm in one launch (block = layer).
__global__ void k_wqm3(const float* __restrict__ Wq_all, const float* __restrict__ bq_all,
                       const float* __restrict__ We_all, float* __restrict__ Wqm3,
                       float* __restrict__ bqm3) {
    int l = blockIdx.x;
    const float* Wq = Wq_all + l * 4096;
    const float* bq = bq_all + l * 64;
    const float* We = We_all + l * 1024;
    float* Wqm = Wqm3 + l * 4096;
    float* bqm = bqm3 + l * 64;
    for (int o = threadIdx.x; o < 64 * 64; o += 256) {
        int j = o >> 6, lp = o & 63, hh = lp >> 4, ii = lp & 15;
        float acc = 0.f;
#pragma unroll
        for (int c = 0; c < 16; ++c)
            acc += Wq[j * 64 + hh * 16 + c] * We[ii * 64 + hh * 16 + c];
        Wqm[o] = acc;
    }
    if (threadIdx.x < 64) {
        int hh = threadIdx.x >> 4, ii = threadIdx.x & 15;
        float acc = 0.f;
#pragma unroll
        for (int c = 0; c < 16; ++c)
            acc += bq[hh * 16 + c] * We[ii * 64 + hh * 16 + c];
        bqm[threadIdx.x] = acc;
    }
}

// qn,tq,sn fp32 + kv fp16 (k|v interleaved per node: kv[n][0..63]=k, [64..127]=v).
// Register-blocked 5-in-1 GEMM; k0 loop sequential (unroll 1) -> no spill.
__global__ __launch_bounds__(256) void k_qkvt(const float* __restrict__ h,
                       const float* __restrict__ Wq, const float* __restrict__ bq,
                       const float* __restrict__ Wk, const float* __restrict__ bk,
                       const float* __restrict__ Wv, const float* __restrict__ bv,
                       const float* __restrict__ Wqm, const float* __restrict__ bqm,
                       const float* __restrict__ Ws, const float* __restrict__ bs,
                       float* __restrict__ qn, __half* __restrict__ kv,
                       float* __restrict__ tq, float* __restrict__ sn) {
    __shared__ float sh[64 * 64];
    int base = blockIdx.x * 64;
    for (int i = threadIdx.x; i < 1024; i += 256) {       // 64 rows x 64 cols, float4
        int off = i * 4, row = off >> 6;
        float4 v = (base + row < Nn) ? ((const float4*)(h))[((size_t)base * 64 + off) >> 2]
                                     : make_float4(0.f, 0.f, 0.f, 0.f);
        ((float4*)sh)[i] = v;
    }
    __syncthreads();
    int lane = threadIdx.x & 63, wv = threadIdx.x >> 6;
    float aq[16], ak[16], av[16], at[16], as_[16];
    float _bq = bq[lane], _bk = bk[lane], _bv = bv[lane], _bt = bqm[lane], _bs = bs[lane];
#pragma unroll
    for (int nn = 0; nn < 16; ++nn) {
        aq[nn] = _bq; ak[nn] = _bk; av[nn] = _bv; at[nn] = _bt; as_[nn] = _bs;
    }
#pragma unroll 1
    for (int k0 = 0; k0 < 64; k0 += 4) {
        float wq[4], wk[4], wvv[4], wt[4], ws[4];
#pragma unroll
        for (int j = 0; j < 4; ++j) {
            wq[j] = Wq[(k0 + j) * 64 + lane];
            wk[j] = Wk[(k0 + j) * 64 + lane];
            wvv[j] = Wv[(k0 + j) * 64 + lane];
            wt[j] = Wqm[(k0 + j) * 64 + lane];
            ws[j] = Ws[(k0 + j) * 64 + lane];
        }
#pragma unroll
        for (int nn = 0; nn < 16; ++nn) {
            int row = wv * 16 + nn;
            float4 hv = *(const float4*)&sh[row * 64 + k0];
            aq[nn] = fmaf(hv.x, wq[0], fmaf(hv.y, wq[1], fmaf(hv.z, wq[2], fmaf(hv.w, wq[3], aq[nn]))));
            ak[nn] = fmaf(hv.x, wk[0], fmaf(hv.y, wk[1], fmaf(hv.z, wk[2], fmaf(hv.w, wk[3], ak[nn]))));
            av[nn] = fmaf(hv.x, wvv[0], fmaf(hv.y, wvv[1], fmaf(hv.z, wvv[2], fmaf(hv.w, wvv[3], av[nn]))));
            at[nn] = fmaf(hv.x, wt[0], fmaf(hv.y, wt[1], fmaf(hv.z, wt[2], fmaf(hv.w, wt[3], at[nn]))));
            as_[nn] = fmaf(hv.x, ws[0], fmaf(hv.y, ws[1], fmaf(hv.z, ws[2], fmaf(hv.w, ws[3], as_[nn]))));
        }
    }
#pragma unroll
    for (int nn = 0; nn < 16; ++nn) {
        int n = base + wv * 16 + nn;
        if (n < Nn) {
            size_t o = (size_t)n * 64 + lane;
            qn[o] = aq[nn]; tq[o] = at[nn]; sn[o] = as_[nn];
            kv[(size_t)n * 128 + lane]      = __float2half_rn(ak[nn]);
            kv[(size_t)n * 128 + 64 + lane] = __float2half_rn(av[nn]);
        }
    }
}

// Fully-fused per-layer edge pass: one wave per dst node, online softmax in
// base-2, 4-edge unroll for ILP. k/v/ea gathered in fp16 (halves gather
// bytes; fp16 0.05% rel err keeps alpha error ~5e-3 -> safe vs threshold;
// bf16 would give ~4% attn shift - too risky). SC folded into q,t at load.
template <bool SORTED>
__global__ __launch_bounds__(256) void k_layer(float* __restrict__ h,
                      const float* __restrict__ qn, const __half* __restrict__ kv,
                      const float* __restrict__ tq, const float* __restrict__ sn,
                      const int* __restrict__ row_ptr, const int* __restrict__ src_perm,
                      const int* __restrict__ eperm, const __half* __restrict__ eah,
                      const float* __restrict__ eaf, const float* __restrict__ We) {
    __shared__ float sWe[1024];
    __shared__ float tile[4][64];
    for (int t = threadIdx.x; t < 1024; t += 256) sWe[t] = We[t];
    __syncthreads();
    int lane = threadIdx.x & 63, wv = threadIdx.x >> 6;
    int hh = lane >> 4, cc = lane & 15;
    int n = blockIdx.x * 4 + wv;
    if (n >= Nn) return;
    int beg = row_ptr[n], end = row_ptr[n + 1];
    const float SC = 0.25f * 1.4426950408889634f;  // 1/sqrt(C) * log2(e)
    float q = qn[(size_t)n * 64 + lane] * SC;
    float t = tq[(size_t)n * 64 + lane] * SC;
    float m = -INFINITY, accd = 0.f, accv = 0.f, acce = 0.f;
    int idx = beg;
    for (; idx + 4 <= end; idx += 4) {
        long b0 = (long)src_perm[idx] * 128,     b1 = (long)src_perm[idx + 1] * 128;
        long b2 = (long)src_perm[idx + 2] * 128, b3 = (long)src_perm[idx + 3] * 128;
        float k0 = __half2float(kv[b0 + lane]),      k1 = __half2float(kv[b1 + lane]);
        float k2 = __half2float(kv[b2 + lane]),      k3 = __half2float(kv[b3 + lane]);
        float v0 = __half2float(kv[b0 + 64 + lane]), v1 = __half2float(kv[b1 + 64 + lane]);
        float v2 = __half2float(kv[b2 + 64 + lane]), v3 = __half2float(kv[b3 + 64 + lane]);
        float x0, x1, x2, x3;
        if (SORTED) {
            long o0 = (long)idx * 16;
            x0 = __half2float(eah[o0 + cc]);      x1 = __half2float(eah[o0 + 16 + cc]);
            x2 = __half2float(eah[o0 + 32 + cc]); x3 = __half2float(eah[o0 + 48 + cc]);
        } else {
            x0 = eaf[(long)eperm[idx] * 16 + cc];     x1 = eaf[(long)eperm[idx + 1] * 16 + cc];
            x2 = eaf[(long)eperm[idx + 2] * 16 + cc]; x3 = eaf[(long)eperm[idx + 3] * 16 + cc];
        }
        float a0 = fmaf(q, k0, x0 * t), a1 = fmaf(q, k1, x1 * t);
        float a2 = fmaf(q, k2, x2 * t), a3 = fmaf(q, k3, x3 * t);
        // 4 independent butterfly chains (scheduler interleaves)
        a0 += __shfl_xor(a0, 1, 16); a1 += __shfl_xor(a1, 1, 16);
        a2 += __shfl_xor(a2, 1, 16); a3 += __shfl_xor(a3, 1, 16);
        a0 += __shfl_xor(a0, 2, 16); a1 += __shfl_xor(a1, 2, 16);
        a2 += __shfl_xor(a2, 2, 16); a3 += __shfl_xor(a3, 2, 16);
        a0 += __shfl_xor(a0, 4, 16); a1 += __shfl_xor(a1, 4, 16);
        a2 += __shfl_xor(a2, 4, 16); a3 += __shfl_xor(a3, 4, 16);
        a0 += __shfl_xor(a0, 8, 16); a1 += __shfl_xor(a1, 8, 16);
        a2 += __shfl_xor(a2, 8, 16); a3 += __shfl_xor(a3, 8, 16);
        float mx = fmaxf(fmaxf(a0, a1), fmaxf(a2, a3));
        float nm = fmaxf(m, mx);
        float w = __builtin_exp2f(m - nm);
        float p0 = __builtin_exp2f(a0 - nm), p1 = __builtin_exp2f(a1 - nm);
        float p2 = __builtin_exp2f(a2 - nm), p3 = __builtin_exp2f(a3 - nm);
        accd = fmaf(accd, w, (p0 + p1) + (p2 + p3));
        accv = fmaf(accv, w, fmaf(p0, v0, fmaf(p1, v1, fmaf(p2, v2, p3 * v3))));
        acce = fmaf(acce, w, fmaf(p0, x0, fmaf(p1, x1, fmaf(p2, x2, p3 * x3))));
        m = nm;
    }
    for (; idx < end; ++idx) {
        long b0 = (long)src_perm[idx] * 128;
        float k0 = __half2float(kv[b0 + lane]);
        float v0 = __half2float(kv[b0 + 64 + lane]);
        float x0 = SORTED ? __half2float(eah[(long)idx * 16 + cc])
                          : eaf[(long)eperm[idx] * 16 + cc];
        float a0 = fmaf(q, k0, x0 * t);
        a0 += __shfl_xor(a0, 1, 16);
        a0 += __shfl_xor(a0, 2, 16);
        a0 += __shfl_xor(a0, 4, 16);
        a0 += __shfl_xor(a0, 8, 16);
        float nm = fmaxf(m, a0);
        float w = __builtin_exp2f(m - nm);
        float p0 = __builtin_exp2f(a0 - nm);
        accd = fmaf(accd, w, p0);
        accv = fmaf(accv, w, p0 * v0);
        acce = fmaf(acce, w, p0 * x0);
        m = nm;
    }
    float inv = 1.f / (accd + 1e-16f);
    tile[wv][lane] = acce * inv;  // wave-local LDS round-trip (lockstep, no barrier)
    float re = 0.f;
#pragma unroll
    for (int i = 0; i < 16; ++i)
        re = fmaf(tile[wv][hh * 16 + i], sWe[i * 64 + lane], re);
    size_t o = (size_t)n * 64 + lane;
    float hv = h[o];
    h[o] = hv + fmaxf(fmaf(accv, inv, re + sn[o]), 0.f);
}

// mean-pool per group (batch sorted -> boundaries) + fused MLP head
__global__ void k_pool(const float* __restrict__ h, const int* __restrict__ gstart,
                       const float* __restrict__ W1, const float* __restrict__ b1,
                       const float* __restrict__ W2, const float* __restrict__ b2,
                       float* __restrict__ out) {
    int g = blockIdx.x;
    int lane = threadIdx.x & 63, wv = threadIdx.x >> 6;
    int beg = gstart[g], end = gstart[g + 1];
    __shared__ float red[4][64];
    __shared__ float sp[64];
    __shared__ float sh[32];
    float acc = 0.f;
    for (int n = beg + wv; n < end; n += 4) acc += h[(size_t)n * 64 + lane];
    red[wv][lane] = acc;
    __syncthreads();
    if (threadIdx.x < 64) {
        float c = fmaxf((float)(end - beg), 1.f);
        sp[lane] = (red[0][lane] + red[1][lane] + red[2][lane] + red[3][lane]) / c;
    }
    __syncthreads();
    if (threadIdx.x < 32) {
        int t = threadIdx.x;
        float a = b1[t];
#pragma unroll
        for (int i = 0; i < 64; ++i) a = fmaf(sp[i], W1[i * 32 + t], a);
        sh[t] = fmaxf(a, 0.f) * W2[t];
    }
    __syncthreads();
    if (threadIdx.x == 0) {
        float s = b2[0];
#pragma unroll
        for (int i = 0; i < 32; ++i) s += sh[i];
        out[g] = s;
    }
}

extern "C" void kernel_launch(void* const* d_in, const int* in_sizes, int n_in,
                              void* d_out, int out_size, void* d_ws, size_t ws_size,
                              hipStream_t stream) {
    const float* x   = (const float*)d_in[0];
    const int*   ei  = (const int*)d_in[1];
    const float* ea  = (const float*)d_in[2];
    const int*   bat = (const int*)d_in[3];
    const float* Wn  = (const float*)d_in[4];
    const float* bn  = (const float*)d_in[5];
    const float* Wq  = (const float*)d_in[6];
    const float* bq  = (const float*)d_in[7];
    const float* Wk  = (const float*)d_in[8];
    const float* bk  = (const float*)d_in[9];
    const float* Wv  = (const float*)d_in[10];
    const float* bv  = (const float*)d_in[11];
    const float* We  = (const float*)d_in[12];
    const float* Wsk = (const float*)d_in[13];
    const float* bs  = (const float*)d_in[14];
    const float* W1  = (const float*)d_in[15];
    const float* b1  = (const float*)d_in[16];
    const float* W2  = (const float*)d_in[17];
    const float* b2  = (const float*)d_in[18];
    float* out = (float*)d_out;

    const size_t NH = (size_t)Nn * 64;
    float* h    = (float*)d_ws;
    float* qn   = h + NH;
    float* tq   = h + 2 * NH;
    float* sn   = h + 3 * NH;
    __half* kv  = (__half*)(h + 4 * NH);       // N*128 half == NH floats of space
    float* Wqm3 = h + 5 * NH;                  // 3*4096
    float* bqm3 = Wqm3 + 3 * 4096;             // 3*64
    int* deg       = (int*)(bqm3 + 3 * 64);    // N
    int* row_ptr   = deg + Nn;                 // N+1
    int* cursor    = row_ptr + Nn + 1;         // N
    int* src_perm  = cursor + Nn;              // E
    int* eperm     = src_perm + Ee;            // E
    int* bsum      = eperm + Ee;               // 256
    int* gstart    = bsum + 256;               // G+1
    __half* ea_h   = (__half*)(gstart + Gg + 1);  // E*16 half (optional)
    size_t need_sorted = ((char*)(ea_h + (size_t)Ee * 16)) - (char*)d_ws;
    bool sorted = ws_size >= need_sorted;      // constant across calls

    const int NB = 196;  // ceil(50000/256)
    hipMemsetAsync(deg, 0, Nn * sizeof(int), stream);
    k_hist<<<(Ee + 255) / 256, 256, 0, stream>>>(ei, deg);
    k_scan1<<<NB, 256, 0, stream>>>(deg, row_ptr, bsum);
    k_scan2<<<1, 256, 0, stream>>>(bsum, NB);
    k_scan3<<<(Nn + 256) / 256, 256, 0, stream>>>(row_ptr, bsum);
    hipMemcpyAsync(cursor, row_ptr, Nn * sizeof(int), hipMemcpyDeviceToDevice, stream);
    k_scatter<<<(Ee + 255) / 256, 256, 0, stream>>>(ei, cursor, src_perm, eperm);
    if (sorted)
        k_easort<<<(Ee * 4 + 255) / 256, 256, 0, stream>>>(ea, eperm, ea_h);
    k_gbound<<<(Nn + 255) / 256, 256, 0, stream>>>(bat, gstart);
    k_wqm3<<<3, 256, 0, stream>>>(Wq, bq, We, Wqm3, bqm3);

    int nodeBlocks = (Nn + 63) / 64;
    k_encode<<<nodeBlocks, 256, 0, stream>>>(x, Wn, bn, h);
    for (int l = 0; l < 3; ++l) {
        k_qkvt<<<nodeBlocks, 256, 0, stream>>>(h, Wq + l * 4096, bq + l * 64,
                                               Wk + l * 4096, bk + l * 64,
                                               Wv + l * 4096, bv + l * 64,
                                               Wqm3 + l * 4096, bqm3 + l * 64,
                                               Wsk + l * 4096, bs + l * 64,
                                               qn, kv, tq, sn);
        if (sorted)
            k_layer<true><<<(Nn + 3) / 4, 256, 0, stream>>>(h, qn, kv, tq, sn,
                    row_ptr, src_perm, eperm, ea_h, ea, We + l * 1024);
        else
            k_layer<false><<<(Nn + 3) / 4, 256, 0, stream>>>(h, qn, kv, tq, sn,
                    row_ptr, src_perm, eperm, ea_h, ea, We + l * 1024);
    }
    k_pool<<<Gg, 256, 0, stream>>>(h, gstart, W1, b1, W2, b2, out);
}